// Round 9
// baseline (402.554 us; speedup 1.0000x reference)
//
#include <hip/hip_runtime.h>

typedef unsigned short u16;
typedef __attribute__((ext_vector_type(8))) __bf16 bf16x8;
typedef __attribute__((ext_vector_type(4))) float f32x4;

#define B_ 2
#define L_ 1024
#define DIM_ 512
#define DINNER_ 1024
#define DSTATE_ 16
#define DTRANK_ 32
#define VOCAB_ 32000
#define NCHUNK 64
#define CLEN 16

__device__ __forceinline__ u16 f2bf(float f) {
    union { float f; unsigned u; } x; x.f = f;
    unsigned r = x.u + 0x7FFFu + ((x.u >> 16) & 1u);
    return (u16)(r >> 16);
}

// ---------------- prep: weight bf16 conversions + dtw transpose + embed+rms ----------------
__global__ __launch_bounds__(256) void prep(const float* __restrict__ in_w,
                                            const float* __restrict__ out_w,
                                            const float* __restrict__ head_w,
                                            const float* __restrict__ dt_w,
                                            const int* __restrict__ x,
                                            const float* __restrict__ embed,
                                            const float* __restrict__ rw,
                                            u16* __restrict__ win,
                                            u16* __restrict__ wout,
                                            u16* __restrict__ whd,
                                            float* __restrict__ dtwT,
                                            float* __restrict__ h,
                                            u16* __restrict__ rbf) {
    int bk = blockIdx.x;
    int t = threadIdx.x;
    if (bk < 19072) {
        const int n1 = 524288;
        const int n2 = n1 + 262144;
        int i = bk * 256 + t;
        const float4* s; ushort4* d; int j;
        if (i < n1)      { s = (const float4*)in_w;   d = (ushort4*)win;  j = i; }
        else if (i < n2) { s = (const float4*)out_w;  d = (ushort4*)wout; j = i - n1; }
        else             { s = (const float4*)head_w; d = (ushort4*)whd;  j = i - n2; }
        float4 v = s[j];
        ushort4 o; o.x = f2bf(v.x); o.y = f2bf(v.y); o.z = f2bf(v.z); o.w = f2bf(v.w);
        d[j] = o;
    } else if (bk < 19328) {
        int bb = bk - 19072;
        int l = bb >> 7;
        int e = (bb & 127) * 256 + t;
        int r = e >> 10, d = e & 1023;
        dtwT[(size_t)l * 32768 + r * 1024 + d] = dt_w[(size_t)l * 32768 + d * 32 + r];
    } else {
        int wave = t >> 6, lane = t & 63;
        int row = (bk - 19328) * 4 + wave;
        int tok = x[row];
        const float4* s = (const float4*)(embed + (size_t)tok * DIM_);
        float4 v0 = s[lane], v1 = s[lane + 64];
        float4* hd = (float4*)(h + (size_t)row * DIM_);
        hd[lane] = v0;
        hd[lane + 64] = v1;
        float ss = v0.x*v0.x + v0.y*v0.y + v0.z*v0.z + v0.w*v0.w
                 + v1.x*v1.x + v1.y*v1.y + v1.z*v1.z + v1.w*v1.w;
        for (int m = 1; m < 64; m <<= 1) ss += __shfl_xor(ss, m);
        float rms = rsqrtf(ss * (1.0f / DIM_) + 1e-5f);
        const float4* w4 = (const float4*)rw;
        float4 w0 = w4[lane], w1 = w4[lane + 64];
        u16* o = rbf + (size_t)row * DIM_;
        ushort4 a, b;
        a.x = f2bf(v0.x * rms * w0.x); a.y = f2bf(v0.y * rms * w0.y);
        a.z = f2bf(v0.z * rms * w0.z); a.w = f2bf(v0.w * rms * w0.w);
        b.x = f2bf(v1.x * rms * w1.x); b.y = f2bf(v1.y * rms * w1.y);
        b.z = f2bf(v1.z * rms * w1.z); b.w = f2bf(v1.w * rms * w1.w);
        *(ushort4*)(o + lane * 4) = a;
        *(ushort4*)(o + 256 + lane * 4) = b;
    }
}

// ---------------- RMSNorm -> bf16 ----------------
__global__ __launch_bounds__(256) void rmsnorm_bf16(const float* __restrict__ h,
                                                    const float* __restrict__ w,
                                                    u16* __restrict__ out) {
    int wave = threadIdx.x >> 6, lane = threadIdx.x & 63;
    int row = blockIdx.x * 4 + wave;
    const float4* r4 = (const float4*)(h + (size_t)row * DIM_);
    float4 v0 = r4[lane], v1 = r4[lane + 64];
    float ss = v0.x*v0.x + v0.y*v0.y + v0.z*v0.z + v0.w*v0.w
             + v1.x*v1.x + v1.y*v1.y + v1.z*v1.z + v1.w*v1.w;
    for (int m = 1; m < 64; m <<= 1) ss += __shfl_xor(ss, m);
    float rms = rsqrtf(ss * (1.0f / DIM_) + 1e-5f);
    const float4* w4 = (const float4*)w;
    float4 w0 = w4[lane], w1 = w4[lane + 64];
    u16* o = out + (size_t)row * DIM_;
    ushort4 a, b;
    a.x = f2bf(v0.x * rms * w0.x); a.y = f2bf(v0.y * rms * w0.y);
    a.z = f2bf(v0.z * rms * w0.z); a.w = f2bf(v0.w * rms * w0.w);
    b.x = f2bf(v1.x * rms * w1.x); b.y = f2bf(v1.y * rms * w1.y);
    b.z = f2bf(v1.z * rms * w1.z); b.w = f2bf(v1.w * rms * w1.w);
    *(ushort4*)(o + lane * 4) = a;
    *(ushort4*)(o + 256 + lane * 4) = b;
}

// ---------------- LayerNorm -> bf16 ----------------
__global__ __launch_bounds__(256) void layernorm_bf16(const float* __restrict__ h,
                                                      const float* __restrict__ g,
                                                      const float* __restrict__ bta,
                                                      u16* __restrict__ out) {
    int wave = threadIdx.x >> 6, lane = threadIdx.x & 63;
    int row = blockIdx.x * 4 + wave;
    const float4* r4 = (const float4*)(h + (size_t)row * DIM_);
    float4 v0 = r4[lane], v1 = r4[lane + 64];
    float s = v0.x + v0.y + v0.z + v0.w + v1.x + v1.y + v1.z + v1.w;
    float ss = v0.x*v0.x + v0.y*v0.y + v0.z*v0.z + v0.w*v0.w
             + v1.x*v1.x + v1.y*v1.y + v1.z*v1.z + v1.w*v1.w;
    for (int m = 1; m < 64; m <<= 1) { s += __shfl_xor(s, m); ss += __shfl_xor(ss, m); }
    float mu = s * (1.0f / DIM_);
    float var = ss * (1.0f / DIM_) - mu * mu;
    float rs = rsqrtf(var + 1e-5f);
    const float4* g4 = (const float4*)g;
    const float4* b4 = (const float4*)bta;
    float4 g0 = g4[lane], g1 = g4[lane + 64];
    float4 b0 = b4[lane], b1 = b4[lane + 64];
    u16* o = out + (size_t)row * DIM_;
    ushort4 a, b;
    a.x = f2bf((v0.x - mu) * rs * g0.x + b0.x); a.y = f2bf((v0.y - mu) * rs * g0.y + b0.y);
    a.z = f2bf((v0.z - mu) * rs * g0.z + b0.z); a.w = f2bf((v0.w - mu) * rs * g0.w + b0.w);
    b.x = f2bf((v1.x - mu) * rs * g1.x + b1.x); b.y = f2bf((v1.y - mu) * rs * g1.y + b1.y);
    b.z = f2bf((v1.z - mu) * rs * g1.z + b1.z); b.w = f2bf((v1.w - mu) * rs * g1.w + b1.w);
    *(ushort4*)(o + lane * 4) = a;
    *(ushort4*)(o + 256 + lane * 4) = b;
}

// ---------------- MFMA GEMM 128x128, BK=32, depth-4 rotation, counted vmcnt ----------------
template <int MODE>
__global__ __launch_bounds__(256) void gemm_bt(const u16* __restrict__ A,
                                               const u16* __restrict__ B,
                                               float* __restrict__ C,
                                               const float* __restrict__ bias,
                                               int M, int N, int K,
                                               int nbx, int swzq) {
    __shared__ u16 As[4][128 * 32];
    __shared__ u16 Bs[4][128 * 32];
    const int tid = threadIdx.x;
    const int wave = tid >> 6;
    const int lane = tid & 63;
    int lin = blockIdx.x;
    if (swzq) lin = (lin & 7) * swzq + (lin >> 3);
    const int m0 = (lin % nbx) * 128;
    const int n0 = (lin / nbx) * 128;
    const int wr = wave >> 1, wc = wave & 1;
    f32x4 acc[4][4] = {};

    const int sub = lane >> 2;
    const int slotL = lane & 3;
    const int fsub = (sub & 3) ^ ((sub >> 2) & 3);
    const int scol = (slotL ^ fsub) * 8;

    auto stage = [&](int buf, int kt) {
        int k0 = kt * 32;
        #pragma unroll
        for (int i = 0; i < 4; ++i) {
            int c = wave * 4 + i;
            const u16* src;
            u16* dst;
            if (c < 8) {
                int row = c * 16 + sub;
                src = A + (size_t)(m0 + row) * K + k0 + scol;
                dst = &As[buf][c * 512];
            } else {
                int cc = c - 8;
                int row = cc * 16 + sub;
                src = B + (size_t)(n0 + row) * K + k0 + scol;
                dst = &Bs[buf][cc * 512];
            }
            __builtin_amdgcn_global_load_lds((const __attribute__((address_space(1))) void*)src,
                                             (__attribute__((address_space(3))) void*)dst,
                                             16, 0, 0);
        }
    };

    const int nt = K / 32;
    stage(0, 0); stage(1, 1); stage(2, 2);

    const int fr = lane & 15;
    const int q = lane >> 4;
    const int fswz = (fr & 3) ^ ((fr >> 2) & 3);
    const int rdoff = ((q ^ fswz) * 8);

    for (int t = 0; t < nt; ++t) {
        if (t + 2 < nt)      asm volatile("s_waitcnt vmcnt(8)" ::: "memory");
        else if (t + 1 < nt) asm volatile("s_waitcnt vmcnt(4)" ::: "memory");
        else                 asm volatile("s_waitcnt vmcnt(0)" ::: "memory");
        __builtin_amdgcn_sched_barrier(0);
        __builtin_amdgcn_s_barrier();
        asm volatile("" ::: "memory");
        __builtin_amdgcn_sched_barrier(0);
        if (t + 3 < nt) stage((t + 3) & 3, t + 3);
        const u16* Ab = &As[t & 3][0];
        const u16* Bb = &Bs[t & 3][0];
        bf16x8 a[4], b[4];
        #pragma unroll
        for (int mi = 0; mi < 4; ++mi)
            a[mi] = *(const bf16x8*)(Ab + (wr * 64 + mi * 16 + fr) * 32 + rdoff);
        #pragma unroll
        for (int ni = 0; ni < 4; ++ni)
            b[ni] = *(const bf16x8*)(Bb + (wc * 64 + ni * 16 + fr) * 32 + rdoff);
        __builtin_amdgcn_s_setprio(1);
        #pragma unroll
        for (int mi = 0; mi < 4; ++mi)
            #pragma unroll
            for (int ni = 0; ni < 4; ++ni)
                acc[mi][ni] = __builtin_amdgcn_mfma_f32_16x16x32_bf16(a[mi], b[ni], acc[mi][ni], 0, 0, 0);
        __builtin_amdgcn_s_setprio(0);
    }

    const int cl = lane & 15;
    const int rq = (lane >> 4) * 4;
    #pragma unroll
    for (int mi = 0; mi < 4; ++mi) {
        #pragma unroll
        for (int ni = 0; ni < 4; ++ni) {
            int col = n0 + wc * 64 + ni * 16 + cl;
            #pragma unroll
            for (int rr = 0; rr < 4; ++rr) {
                int row = m0 + wr * 64 + mi * 16 + rq + rr;
                size_t idx = (size_t)row * N + col;
                float v = acc[mi][ni][rr];
                if (MODE == 2)      C[idx] = v + bias[col];
                else                C[idx] = v;
            }
        }
    }
}

// ---------------- MFMA GEMM 256x256 (head), BK=32, 512 thr, depth-4 rotation ----------------
__global__ __launch_bounds__(512) void gemm256(const u16* __restrict__ A,
                                               const u16* __restrict__ B,
                                               float* __restrict__ C,
                                               const float* __restrict__ bias,
                                               int M, int N, int K,
                                               int nbx, int swzq) {
    __shared__ u16 As[4][256 * 32];
    __shared__ u16 Bs[4][256 * 32];
    const int tid = threadIdx.x;
    const int wave = tid >> 6;
    const int lane = tid & 63;
    int lin = blockIdx.x;
    if (swzq) lin = (lin & 7) * swzq + (lin >> 3);
    const int m0 = (lin % nbx) * 256;
    const int n0 = (lin / nbx) * 256;
    const int wrM = wave >> 2;
    const int wcN = wave & 3;
    f32x4 acc[8][4] = {};

    const int sub = lane >> 2;
    const int slotL = lane & 3;
    const int fsub = (sub & 3) ^ ((sub >> 2) & 3);
    const int scol = (slotL ^ fsub) * 8;

    auto stage = [&](int buf, int kt) {
        int k0 = kt * 32;
        #pragma unroll
        for (int i = 0; i < 4; ++i) {
            int c = wave * 4 + i;
            const u16* src;
            u16* dst;
            if (c < 16) {
                int row = c * 16 + sub;
                src = A + (size_t)(m0 + row) * K + k0 + scol;
                dst = &As[buf][c * 512];
            } else {
                int cc = c - 16;
                int row = cc * 16 + sub;
                src = B + (size_t)(n0 + row) * K + k0 + scol;
                dst = &Bs[buf][cc * 512];
            }
            __builtin_amdgcn_global_load_lds((const __attribute__((address_space(1))) void*)src,
                                             (__attribute__((address_space(3))) void*)dst,
                                             16, 0, 0);
        }
    };

    const int nt = K / 32;
    stage(0, 0); stage(1, 1); stage(2, 2);

    const int fr = lane & 15;
    const int q = lane >> 4;
    const int fswz = (fr & 3) ^ ((fr >> 2) & 3);
    const int rdoff = ((q ^ fswz) * 8);

    for (int t = 0; t < nt; ++t) {
        if (t + 2 < nt)      asm volatile("s_waitcnt vmcnt(8)" ::: "memory");
        else if (t + 1 < nt) asm volatile("s_waitcnt vmcnt(4)" ::: "memory");
        else                 asm volatile("s_waitcnt vmcnt(0)" ::: "memory");
        __builtin_amdgcn_sched_barrier(0);
        __builtin_amdgcn_s_barrier();
        asm volatile("" ::: "memory");
        __builtin_amdgcn_sched_barrier(0);
        if (t + 3 < nt) stage((t + 3) & 3, t + 3);
        const u16* Ab = &As[t & 3][0];
        const u16* Bb = &Bs[t & 3][0];
        bf16x8 a[8], b[4];
        #pragma unroll
        for (int mi = 0; mi < 8; ++mi)
            a[mi] = *(const bf16x8*)(Ab + (wrM * 128 + mi * 16 + fr) * 32 + rdoff);
        #pragma unroll
        for (int ni = 0; ni < 4; ++ni)
            b[ni] = *(const bf16x8*)(Bb + (wcN * 64 + ni * 16 + fr) * 32 + rdoff);
        __builtin_amdgcn_s_setprio(1);
        #pragma unroll
        for (int mi = 0; mi < 8; ++mi)
            #pragma unroll
            for (int ni = 0; ni < 4; ++ni)
                acc[mi][ni] = __builtin_amdgcn_mfma_f32_16x16x32_bf16(a[mi], b[ni], acc[mi][ni], 0, 0, 0);
        __builtin_amdgcn_s_setprio(0);
    }

    const int cl = lane & 15;
    const int rq = (lane >> 4) * 4;
    #pragma unroll
    for (int mi = 0; mi < 8; ++mi) {
        #pragma unroll
        for (int ni = 0; ni < 4; ++ni) {
            int col = n0 + wcN * 64 + ni * 16 + cl;
            float bv = bias[col];
            #pragma unroll
            for (int rr = 0; rr < 4; ++rr) {
                int row = m0 + wrM * 128 + mi * 16 + rq + rr;
                C[(size_t)row * N + col] = acc[mi][ni][rr] + bv;
            }
        }
    }
}

// ---------------- MFMA GEMM 64x64, BK=64, depth-4 rotation, counted vmcnt ----------------
template <int MODE>
__global__ __launch_bounds__(256) void gemm64(const u16* __restrict__ A,
                                              const u16* __restrict__ B,
                                              float* __restrict__ C,
                                              int M, int N, int K,
                                              int nbx, int swzq) {
    __shared__ u16 As[4][64 * 64];
    __shared__ u16 Bs[4][64 * 64];
    const int tid = threadIdx.x;
    const int wave = tid >> 6;
    const int lane = tid & 63;
    int lin = blockIdx.x;
    if (swzq) lin = (lin & 7) * swzq + (lin >> 3);
    const int m0 = (lin % nbx) * 64;
    const int n0 = (lin / nbx) * 64;
    const int wr = wave >> 1, wc = wave & 1;
    f32x4 acc[2][2] = {};

    const int crow = lane >> 3;
    const int scol = ((lane & 7) ^ crow) * 8;

    auto stage = [&](int buf, int kt) {
        int k0 = kt * 64;
        #pragma unroll
        for (int i = 0; i < 4; ++i) {
            int c = wave * 4 + i;
            const u16* src;
            u16* dst;
            if (c < 8) {
                int row = c * 8 + crow;
                src = A + (size_t)(m0 + row) * K + k0 + scol;
                dst = &As[buf][c * 512];
            } else {
                int cc = c - 8;
                int row = cc * 8 + crow;
                src = B + (size_t)(n0 + row) * K + k0 + scol;
                dst = &Bs[buf][cc * 512];
            }
            __builtin_amdgcn_global_load_lds((const __attribute__((address_space(1))) void*)src,
                                             (__attribute__((address_space(3))) void*)dst,
                                             16, 0, 0);
        }
    };

    const int nt = K / 64;
    stage(0, 0); stage(1, 1); stage(2, 2);

    const int fr = lane & 15;
    const int q = lane >> 4;

    for (int t = 0; t < nt; ++t) {
        if (t + 2 < nt)      asm volatile("s_waitcnt vmcnt(8)" ::: "memory");
        else if (t + 1 < nt) asm volatile("s_waitcnt vmcnt(4)" ::: "memory");
        else                 asm volatile("s_waitcnt vmcnt(0)" ::: "memory");
        __builtin_amdgcn_sched_barrier(0);
        __builtin_amdgcn_s_barrier();
        asm volatile("" ::: "memory");
        __builtin_amdgcn_sched_barrier(0);
        if (t + 3 < nt) stage((t + 3) & 3, t + 3);
        const u16* Ab = &As[t & 3][0];
        const u16* Bb = &Bs[t & 3][0];
        bf16x8 a[2][2], b[2][2];
        #pragma unroll
        for (int ki = 0; ki < 2; ++ki) {
            #pragma unroll
            for (int mi = 0; mi < 2; ++mi) {
                int row = wr * 32 + mi * 16 + fr;
                a[ki][mi] = *(const bf16x8*)(Ab + row * 64 + ((((ki << 2) + q) ^ (fr & 7)) * 8));
            }
            #pragma unroll
            for (int ni = 0; ni < 2; ++ni) {
                int row = wc * 32 + ni * 16 + fr;
                b[ki][ni] = *(const bf16x8*)(Bb + row * 64 + ((((ki << 2) + q) ^ (fr & 7)) * 8));
            }
        }
        __builtin_amdgcn_s_setprio(1);
        #pragma unroll
        for (int ki = 0; ki < 2; ++ki)
            #pragma unroll
            for (int mi = 0; mi < 2; ++mi)
                #pragma unroll
                for (int ni = 0; ni < 2; ++ni)
                    acc[mi][ni] = __builtin_amdgcn_mfma_f32_16x16x32_bf16(a[ki][mi], b[ki][ni], acc[mi][ni], 0, 0, 0);
        __builtin_amdgcn_s_setprio(0);
    }

    const int cl = lane & 15;
    const int rq = (lane >> 4) * 4;
    #pragma unroll
    for (int mi = 0; mi < 2; ++mi) {
        #pragma unroll
        for (int ni = 0; ni < 2; ++ni) {
            int col = n0 + wc * 32 + ni * 16 + cl;
            #pragma unroll
            for (int rr = 0; rr < 4; ++rr) {
                int row = m0 + wr * 32 + mi * 16 + rq + rr;
                size_t idx = (size_t)row * N + col;
                float v = acc[mi][ni][rr];
                if (MODE == 1)      C[idx] += v;
                else                C[idx] = v;
            }
        }
    }
}

// ---------------- fused conv+silu -> xproj -> dt+softplus (8 rows/block) ----------------
__global__ __launch_bounds__(256) void conv_xproj_dt(const float* __restrict__ xz,
                                                     const float* __restrict__ cw,
                                                     const float* __restrict__ cb,
                                                     const float* __restrict__ xw,
                                                     const float* __restrict__ dtwT,
                                                     const float* __restrict__ dtb,
                                                     float* __restrict__ xc,
                                                     float* __restrict__ dbc,
                                                     float* __restrict__ delta) {
    __shared__ float sxc[8 * 1024];
    __shared__ float sxw[64 * 132];
    __shared__ float sred[4][8][68];
    __shared__ float sdbc[8][64];
    int t = threadIdx.x;
    int m0 = blockIdx.x * 8;
    #pragma unroll
    for (int i = 0; i < 32; ++i) {
        int idx = t + i * 256;
        int mi = idx >> 10, d = idx & 1023;
        int m = m0 + mi;
        int l = m & (L_ - 1);
        float acc = cb[d];
        #pragma unroll
        for (int j = 0; j < 4; ++j) {
            int ll = l - 3 + j;
            if (ll >= 0) acc = fmaf(cw[d * 4 + j], xz[(size_t)(m - 3 + j) * (2 * DINNER_) + d], acc);
        }
        float sv = acc / (1.0f + __expf(-acc));
        sxc[mi * 1024 + d] = sv;
        xc[(size_t)m * DINNER_ + d] = sv;
    }
    const int n = t & 63, kg = t >> 6;
    float acc8[8] = {};
    for (int kc = 0; kc < 8; ++kc) {
        __syncthreads();
        #pragma unroll
        for (int i = 0; i < 8; ++i) {
            int f = t + i * 256;
            int row = f >> 5, col4 = f & 31;
            *(float4*)(&sxw[row * 132 + col4 * 4]) =
                *(const float4*)(xw + (size_t)row * DINNER_ + kc * 128 + col4 * 4);
        }
        __syncthreads();
        #pragma unroll
        for (int k4i = 0; k4i < 8; ++k4i) {
            int k4 = kg * 8 + k4i;
            float4 wv = *(const float4*)(&sxw[n * 132 + k4 * 4]);
            #pragma unroll
            for (int mi = 0; mi < 8; ++mi) {
                float4 xv = *(const float4*)(&sxc[mi * 1024 + kc * 128 + k4 * 4]);
                acc8[mi] += wv.x * xv.x + wv.y * xv.y + wv.z * xv.z + wv.w * xv.w;
            }
        }
    }
    #pragma unroll
    for (int mi = 0; mi < 8; ++mi) sred[kg][mi][n] = acc8[mi];
    __syncthreads();
    #pragma unroll
    for (int rep = 0; rep < 2; ++rep) {
        int o = t + rep * 256;
        int mi = o >> 6, n2 = o & 63;
        float v = sred[0][mi][n2] + sred[1][mi][n2] + sred[2][mi][n2] + sred[3][mi][n2];
        sdbc[mi][n2] = v;
        dbc[(size_t)(m0 + mi) * 64 + n2] = v;
    }
    __syncthreads();
    {
        int d0 = t * 4;
        float4 bias = *(const float4*)(dtb + d0);
        float4 am[8];
        #pragma unroll
        for (int mi = 0; mi < 8; ++mi) am[mi] = bias;
        const float4* wT = (const float4*)dtwT;
        #pragma unroll
        for (int r = 0; r < 32; ++r) {
            float4 wv = wT[r * 256 + t];
            #pragma unroll
            for (int mi = 0; mi < 8; ++mi) {
                float s = sdbc[mi][r];
                am[mi].x = fmaf(s, wv.x, am[mi].x);
                am[mi].y = fmaf(s, wv.y, am[mi].y);
                am[mi].z = fmaf(s, wv.z, am[mi].z);
                am[mi].w = fmaf(s, wv.w, am[mi].w);
            }
        }
        #pragma unroll
        for (int mi = 0; mi < 8; ++mi) {
            float4 o;
            o.x = (am[mi].x > 20.f) ? am[mi].x : log1pf(__expf(am[mi].x));
            o.y = (am[mi].y > 20.f) ? am[mi].y : log1pf(__expf(am[mi].y));
            o.z = (am[mi].z > 20.f) ? am[mi].z : log1pf(__expf(am[mi].z));
            o.w = (am[mi].w > 20.f) ? am[mi].w : log1pf(__expf(am[mi].w));
            *(float4*)(delta + (size_t)(m0 + mi) * DINNER_ + d0) = o;
        }
    }
}

// ---------------- fused SSM: local scan + carry + rescan, hfin in LDS ----------------
// grid: 256 blocks = (b = blk>>7, dgroup = blk&127 -> 8 d's); 256 threads.
__global__ __launch_bounds__(256) void ssm_fused(const float* __restrict__ delta,
                                                 const float* __restrict__ xc,
                                                 const float* __restrict__ dbc,
                                                 const float* __restrict__ xz,
                                                 const float* __restrict__ A_log,
                                                 const float* __restrict__ Dp,
                                                 u16* __restrict__ ys) {
    __shared__ float hfin[NCHUNK][8][16];   // 32 KB; phase B rewrites in place with h0
    __shared__ float ssum[NCHUNK][8];       // 2 KB
    const int t = threadIdx.x;
    const int b = blockIdx.x >> 7;
    const int d0 = (blockIdx.x & 127) * 8;

    // ---- phase A: per-chunk local scan (h0 = 0), thread = (dl = t&7, cp = t>>3) ----
    const int dl = t & 7;
    const int cp = t >> 3;                  // 0..31, handles c = cp and cp+32
    const int d = d0 + dl;
    float A[16];
    {
        const float4* Ar = (const float4*)(A_log + (size_t)d * DSTATE_);
        #pragma unroll
        for (int i = 0; i < 4; ++i) {
            float4 al = Ar[i];
            A[i * 4 + 0] = -__expf(al.x); A[i * 4 + 1] = -__expf(al.y);
            A[i * 4 + 2] = -__expf(al.z); A[i * 4 + 3] = -__expf(al.w);
        }
    }
    #pragma unroll
    for (int u = 0; u < 2; ++u) {
        int c = cp + u * 32;
        size_t mrow = (size_t)b * L_ + c * CLEN;
        size_t base = mrow * DINNER_ + d;
        float h[16];
        #pragma unroll
        for (int s = 0; s < 16; ++s) h[s] = 0.f;
        float sd = 0.f;
        #pragma unroll
        for (int l = 0; l < CLEN; ++l) {
            float dv = delta[base + (size_t)l * DINNER_];
            float xv = xc[base + (size_t)l * DINNER_];
            const float4* B4 = (const float4*)(dbc + (mrow + l) * 64 + DTRANK_);
            sd += dv;
            float dx = dv * xv;
            #pragma unroll
            for (int i = 0; i < 4; ++i) {
                float4 bv = B4[i];
                h[i*4+0] = fmaf(__expf(dv * A[i*4+0]), h[i*4+0], dx * bv.x);
                h[i*4+1] = fmaf(__expf(dv * A[i*4+1]), h[i*4+1], dx * bv.y);
                h[i*4+2] = fmaf(__expf(dv * A[i*4+2]), h[i*4+2], dx * bv.z);
                h[i*4+3] = fmaf(__expf(dv * A[i*4+3]), h[i*4+3], dx * bv.w);
            }
        }
        #pragma unroll
        for (int i = 0; i < 4; ++i) {
            float4 v; v.x = h[i*4]; v.y = h[i*4+1]; v.z = h[i*4+2]; v.w = h[i*4+3];
            *(float4*)(&hfin[c][dl][i * 4]) = v;
        }
        ssum[c][dl] = sd;
    }
    __syncthreads();

    // ---- phase B: carry across chunks (LDS-only), threads 0..127 = (dl2 = t>>4, s = t&15) ----
    if (t < 128) {
        int s = t & 15;
        int dl2 = t >> 4;
        float As_ = -__expf(A_log[(size_t)(d0 + dl2) * DSTATE_ + s]);
        float hc = 0.f;
        #pragma unroll 4
        for (int c = 0; c < NCHUNK; ++c) {
            float hf = hfin[c][dl2][s];
            float sd = ssum[c][dl2];
            hfin[c][dl2][s] = hc;             // becomes h0 for chunk c
            hc = fmaf(__expf(As_ * sd), hc, hf);
        }
    }
    __syncthreads();

    // ---- phase C: rescan with carry + y + gate -> ys ----
    float Dval = Dp[d];
    #pragma unroll
    for (int u = 0; u < 2; ++u) {
        int c = cp + u * 32;
        size_t mrow = (size_t)b * L_ + c * CLEN;
        size_t base = mrow * DINNER_ + d;
        size_t zbase = mrow * (2 * DINNER_) + DINNER_ + d;
        float h[16];
        #pragma unroll
        for (int i = 0; i < 4; ++i) {
            float4 v = *(const float4*)(&hfin[c][dl][i * 4]);
            h[i*4+0] = v.x; h[i*4+1] = v.y; h[i*4+2] = v.z; h[i*4+3] = v.w;
        }
        #pragma unroll
        for (int l = 0; l < CLEN; ++l) {
            float dv = delta[base + (size_t)l * DINNER_];
            float xv = xc[base + (size_t)l * DINNER_];
            float zv = xz[zbase + (size_t)l * (2 * DINNER_)];
            const float4* B4 = (const float4*)(dbc + (mrow + l) * 64 + DTRANK_);
            const float4* C4 = (const float4*)(dbc + (mrow + l) * 64 + DTRANK_ + DSTATE_);
            float dx = dv * xv;
            float y = 0.f;
            #pragma unroll
            for (int i = 0; i < 4; ++i) {
                float4 bv = B4[i];
                float4 cv = C4[i];
                h[i*4+0] = fmaf(__expf(dv * A[i*4+0]), h[i*4+0], dx * bv.x);
                h[i*4+1] = fmaf(__expf(dv * A[i*4+1]), h[i*4+1], dx * bv.y);
                h[i*4+2] = fmaf(__expf(dv * A[i*4+2]), h[i*4+2], dx * bv.z);
                h[i*4+3] = fmaf(__expf(dv * A[i*4+3]), h[i*4+3], dx * bv.w);
                y = fmaf(h[i*4+0], cv.x, y);
                y = fmaf(h[i*4+1], cv.y, y);
                y = fmaf(h[i*4+2], cv.z, y);
                y = fmaf(h[i*4+3], cv.w, y);
            }
            y = fmaf(Dval, xv, y);
            float sg = zv / (1.0f + __expf(-zv));
            ys[base + (size_t)l * DINNER_] = f2bf(y * sg);
        }
    }
}

extern "C" void kernel_launch(void* const* d_in, const int* in_sizes, int n_in,
                              void* d_out, int out_size, void* d_ws, size_t ws_size,
                              hipStream_t stream) {
    const int*   x       = (const int*)d_in[0];
    const float* embed   = (const float*)d_in[1];
    const float* rms_w   = (const float*)d_in[2];
    const float* in_w    = (const float*)d_in[3];
    const float* conv_w  = (const float*)d_in[4];
    const float* conv_b  = (const float*)d_in[5];
    const float* xproj_w = (const float*)d_in[6];
    const float* dt_w    = (const float*)d_in[7];
    const float* dt_b    = (const float*)d_in[8];
    const float* A_log   = (const float*)d_in[9];
    const float* Dp      = (const float*)d_in[10];
    const float* out_w   = (const float*)d_in[11];
    const float* ln_g    = (const float*)d_in[12];
    const float* ln_b    = (const float*)d_in[13];
    const float* head_w  = (const float*)d_in[14];
    const float* head_b  = (const float*)d_in[15];
    float* out = (float*)d_out;

    char* p = (char*)d_ws;
    auto take = [&](size_t n) { char* q = p; p += (n + 255) & ~(size_t)255; return q; };
    float* h    = (float*)take(2048ull * 512 * 4);
    u16*   r_bf = (u16*)  take(2048ull * 512 * 2);
    float* xz   = (float*)take(2048ull * 2048 * 4);
    float* xc   = (float*)take(2048ull * 1024 * 4);
    float* dbc  = (float*)take(2048ull * 64 * 4);
    float* dlt  = (float*)take(2048ull * 1024 * 4);
    u16*   ys   = (u16*)  take(2048ull * 1024 * 2);
    u16*   hn   = (u16*)  take(2048ull * 512 * 2);
    u16*   win  = (u16*)  take(2ull * 2048 * 512 * 2);
    u16*   wout = (u16*)  take(2ull * 512 * 1024 * 2);
    u16*   whd  = (u16*)  take(32000ull * 512 * 2);
    float* dtwT = (float*)take(2ull * 32 * 1024 * 4);

    prep<<<19840, 256, 0, stream>>>(in_w, out_w, head_w, dt_w, x, embed, rms_w,
                                    win, wout, whd, dtwT, h, r_bf);

    for (int l = 0; l < 2; ++l) {
        if (l > 0) rmsnorm_bf16<<<512, 256, 0, stream>>>(h, rms_w + l * DIM_, r_bf);
        // xz = r_bf(2048x512) @ win^T(2048x512) : 128^2 tiles, grid 16x16=256, swzq=32
        gemm_bt<0><<<256, 256, 0, stream>>>(r_bf, win + (size_t)l * 2048 * 512, xz, nullptr, 2048, 2048, 512, 16, 32);
        conv_xproj_dt<<<256, 256, 0, stream>>>(xz, conv_w + l * DINNER_ * 4, conv_b + l * DINNER_,
                                               xproj_w + (size_t)l * 64 * 1024,
                                               dtwT + (size_t)l * 32 * 1024, dt_b + l * DINNER_,
                                               xc, dbc, dlt);
        ssm_fused<<<256, 256, 0, stream>>>(dlt, xc, dbc, xz, A_log + (size_t)l * DINNER_ * DSTATE_,
                                           Dp + l * DINNER_, ys);
        // h += ys(2048x1024) @ wout^T(512x1024) : grid 32x8=256, swzq=32
        gemm64<1><<<256, 256, 0, stream>>>(ys, wout + (size_t)l * 512 * 1024, h, 2048, 512, 1024, 32, 32);
    }

    layernorm_bf16<<<512, 256, 0, stream>>>(h, ln_g, ln_b, hn);
    // logits = hn(2048x512) @ whd^T(32000x512) + head_b : 256^2 tiles, grid 8x125=1000, swzq=125
    gemm256<<<1000, 512, 0, stream>>>(hn, whd, out, head_b, 2048, VOCAB_, 512, 8, 125);
}

// Round 10
// 341.717 us; speedup vs baseline: 1.1780x; 1.1780x over previous
//
#include <hip/hip_runtime.h>

typedef unsigned short u16;
typedef __attribute__((ext_vector_type(8))) __bf16 bf16x8;
typedef __attribute__((ext_vector_type(4))) float f32x4;

#define B_ 2
#define L_ 1024
#define DIM_ 512
#define DINNER_ 1024
#define DSTATE_ 16
#define DTRANK_ 32
#define VOCAB_ 32000
#define NCHUNK 64
#define CLEN 16

__device__ __forceinline__ u16 f2bf(float f) {
    union { float f; unsigned u; } x; x.f = f;
    unsigned r = x.u + 0x7FFFu + ((x.u >> 16) & 1u);
    return (u16)(r >> 16);
}

// ---------------- prep: weight bf16 conversions + dtw transpose + embed+rms ----------------
__global__ __launch_bounds__(256) void prep(const float* __restrict__ in_w,
                                            const float* __restrict__ out_w,
                                            const float* __restrict__ head_w,
                                            const float* __restrict__ dt_w,
                                            const int* __restrict__ x,
                                            const float* __restrict__ embed,
                                            const float* __restrict__ rw,
                                            u16* __restrict__ win,
                                            u16* __restrict__ wout,
                                            u16* __restrict__ whd,
                                            float* __restrict__ dtwT,
                                            float* __restrict__ h,
                                            u16* __restrict__ rbf) {
    int bk = blockIdx.x;
    int t = threadIdx.x;
    if (bk < 19072) {
        const int n1 = 524288;
        const int n2 = n1 + 262144;
        int i = bk * 256 + t;
        const float4* s; ushort4* d; int j;
        if (i < n1)      { s = (const float4*)in_w;   d = (ushort4*)win;  j = i; }
        else if (i < n2) { s = (const float4*)out_w;  d = (ushort4*)wout; j = i - n1; }
        else             { s = (const float4*)head_w; d = (ushort4*)whd;  j = i - n2; }
        float4 v = s[j];
        ushort4 o; o.x = f2bf(v.x); o.y = f2bf(v.y); o.z = f2bf(v.z); o.w = f2bf(v.w);
        d[j] = o;
    } else if (bk < 19328) {
        int bb = bk - 19072;
        int l = bb >> 7;
        int e = (bb & 127) * 256 + t;
        int r = e >> 10, d = e & 1023;
        dtwT[(size_t)l * 32768 + r * 1024 + d] = dt_w[(size_t)l * 32768 + d * 32 + r];
    } else {
        int wave = t >> 6, lane = t & 63;
        int row = (bk - 19328) * 4 + wave;
        int tok = x[row];
        const float4* s = (const float4*)(embed + (size_t)tok * DIM_);
        float4 v0 = s[lane], v1 = s[lane + 64];
        float4* hd = (float4*)(h + (size_t)row * DIM_);
        hd[lane] = v0;
        hd[lane + 64] = v1;
        float ss = v0.x*v0.x + v0.y*v0.y + v0.z*v0.z + v0.w*v0.w
                 + v1.x*v1.x + v1.y*v1.y + v1.z*v1.z + v1.w*v1.w;
        for (int m = 1; m < 64; m <<= 1) ss += __shfl_xor(ss, m);
        float rms = rsqrtf(ss * (1.0f / DIM_) + 1e-5f);
        const float4* w4 = (const float4*)rw;
        float4 w0 = w4[lane], w1 = w4[lane + 64];
        u16* o = rbf + (size_t)row * DIM_;
        ushort4 a, b;
        a.x = f2bf(v0.x * rms * w0.x); a.y = f2bf(v0.y * rms * w0.y);
        a.z = f2bf(v0.z * rms * w0.z); a.w = f2bf(v0.w * rms * w0.w);
        b.x = f2bf(v1.x * rms * w1.x); b.y = f2bf(v1.y * rms * w1.y);
        b.z = f2bf(v1.z * rms * w1.z); b.w = f2bf(v1.w * rms * w1.w);
        *(ushort4*)(o + lane * 4) = a;
        *(ushort4*)(o + 256 + lane * 4) = b;
    }
}

// ---------------- RMSNorm -> bf16 ----------------
__global__ __launch_bounds__(256) void rmsnorm_bf16(const float* __restrict__ h,
                                                    const float* __restrict__ w,
                                                    u16* __restrict__ out) {
    int wave = threadIdx.x >> 6, lane = threadIdx.x & 63;
    int row = blockIdx.x * 4 + wave;
    const float4* r4 = (const float4*)(h + (size_t)row * DIM_);
    float4 v0 = r4[lane], v1 = r4[lane + 64];
    float ss = v0.x*v0.x + v0.y*v0.y + v0.z*v0.z + v0.w*v0.w
             + v1.x*v1.x + v1.y*v1.y + v1.z*v1.z + v1.w*v1.w;
    for (int m = 1; m < 64; m <<= 1) ss += __shfl_xor(ss, m);
    float rms = rsqrtf(ss * (1.0f / DIM_) + 1e-5f);
    const float4* w4 = (const float4*)w;
    float4 w0 = w4[lane], w1 = w4[lane + 64];
    u16* o = out + (size_t)row * DIM_;
    ushort4 a, b;
    a.x = f2bf(v0.x * rms * w0.x); a.y = f2bf(v0.y * rms * w0.y);
    a.z = f2bf(v0.z * rms * w0.z); a.w = f2bf(v0.w * rms * w0.w);
    b.x = f2bf(v1.x * rms * w1.x); b.y = f2bf(v1.y * rms * w1.y);
    b.z = f2bf(v1.z * rms * w1.z); b.w = f2bf(v1.w * rms * w1.w);
    *(ushort4*)(o + lane * 4) = a;
    *(ushort4*)(o + 256 + lane * 4) = b;
}

// ---------------- LayerNorm -> bf16 ----------------
__global__ __launch_bounds__(256) void layernorm_bf16(const float* __restrict__ h,
                                                      const float* __restrict__ g,
                                                      const float* __restrict__ bta,
                                                      u16* __restrict__ out) {
    int wave = threadIdx.x >> 6, lane = threadIdx.x & 63;
    int row = blockIdx.x * 4 + wave;
    const float4* r4 = (const float4*)(h + (size_t)row * DIM_);
    float4 v0 = r4[lane], v1 = r4[lane + 64];
    float s = v0.x + v0.y + v0.z + v0.w + v1.x + v1.y + v1.z + v1.w;
    float ss = v0.x*v0.x + v0.y*v0.y + v0.z*v0.z + v0.w*v0.w
             + v1.x*v1.x + v1.y*v1.y + v1.z*v1.z + v1.w*v1.w;
    for (int m = 1; m < 64; m <<= 1) { s += __shfl_xor(s, m); ss += __shfl_xor(ss, m); }
    float mu = s * (1.0f / DIM_);
    float var = ss * (1.0f / DIM_) - mu * mu;
    float rs = rsqrtf(var + 1e-5f);
    const float4* g4 = (const float4*)g;
    const float4* b4 = (const float4*)bta;
    float4 g0 = g4[lane], g1 = g4[lane + 64];
    float4 b0 = b4[lane], b1 = b4[lane + 64];
    u16* o = out + (size_t)row * DIM_;
    ushort4 a, b;
    a.x = f2bf((v0.x - mu) * rs * g0.x + b0.x); a.y = f2bf((v0.y - mu) * rs * g0.y + b0.y);
    a.z = f2bf((v0.z - mu) * rs * g0.z + b0.z); a.w = f2bf((v0.w - mu) * rs * g0.w + b0.w);
    b.x = f2bf((v1.x - mu) * rs * g1.x + b1.x); b.y = f2bf((v1.y - mu) * rs * g1.y + b1.y);
    b.z = f2bf((v1.z - mu) * rs * g1.z + b1.z); b.w = f2bf((v1.w - mu) * rs * g1.w + b1.w);
    *(ushort4*)(o + lane * 4) = a;
    *(ushort4*)(o + 256 + lane * 4) = b;
}

// ---------------- MFMA GEMM 128x128, BK=32, depth-4 rotation, counted vmcnt ----------------
template <int MODE>
__global__ __launch_bounds__(256) void gemm_bt(const u16* __restrict__ A,
                                               const u16* __restrict__ B,
                                               float* __restrict__ C,
                                               const float* __restrict__ bias,
                                               int M, int N, int K,
                                               int nbx, int swzq) {
    __shared__ u16 As[4][128 * 32];
    __shared__ u16 Bs[4][128 * 32];
    const int tid = threadIdx.x;
    const int wave = tid >> 6;
    const int lane = tid & 63;
    int lin = blockIdx.x;
    if (swzq) lin = (lin & 7) * swzq + (lin >> 3);
    const int m0 = (lin % nbx) * 128;
    const int n0 = (lin / nbx) * 128;
    const int wr = wave >> 1, wc = wave & 1;
    f32x4 acc[4][4] = {};

    const int sub = lane >> 2;
    const int slotL = lane & 3;
    const int fsub = (sub & 3) ^ ((sub >> 2) & 3);
    const int scol = (slotL ^ fsub) * 8;

    auto stage = [&](int buf, int kt) {
        int k0 = kt * 32;
        #pragma unroll
        for (int i = 0; i < 4; ++i) {
            int c = wave * 4 + i;
            const u16* src;
            u16* dst;
            if (c < 8) {
                int row = c * 16 + sub;
                src = A + (size_t)(m0 + row) * K + k0 + scol;
                dst = &As[buf][c * 512];
            } else {
                int cc = c - 8;
                int row = cc * 16 + sub;
                src = B + (size_t)(n0 + row) * K + k0 + scol;
                dst = &Bs[buf][cc * 512];
            }
            __builtin_amdgcn_global_load_lds((const __attribute__((address_space(1))) void*)src,
                                             (__attribute__((address_space(3))) void*)dst,
                                             16, 0, 0);
        }
    };

    const int nt = K / 32;
    stage(0, 0); stage(1, 1); stage(2, 2);

    const int fr = lane & 15;
    const int q = lane >> 4;
    const int fswz = (fr & 3) ^ ((fr >> 2) & 3);
    const int rdoff = ((q ^ fswz) * 8);

    for (int t = 0; t < nt; ++t) {
        if (t + 2 < nt)      asm volatile("s_waitcnt vmcnt(8)" ::: "memory");
        else if (t + 1 < nt) asm volatile("s_waitcnt vmcnt(4)" ::: "memory");
        else                 asm volatile("s_waitcnt vmcnt(0)" ::: "memory");
        __builtin_amdgcn_sched_barrier(0);
        __builtin_amdgcn_s_barrier();
        asm volatile("" ::: "memory");
        __builtin_amdgcn_sched_barrier(0);
        if (t + 3 < nt) stage((t + 3) & 3, t + 3);
        const u16* Ab = &As[t & 3][0];
        const u16* Bb = &Bs[t & 3][0];
        bf16x8 a[4], b[4];
        #pragma unroll
        for (int mi = 0; mi < 4; ++mi)
            a[mi] = *(const bf16x8*)(Ab + (wr * 64 + mi * 16 + fr) * 32 + rdoff);
        #pragma unroll
        for (int ni = 0; ni < 4; ++ni)
            b[ni] = *(const bf16x8*)(Bb + (wc * 64 + ni * 16 + fr) * 32 + rdoff);
        __builtin_amdgcn_s_setprio(1);
        #pragma unroll
        for (int mi = 0; mi < 4; ++mi)
            #pragma unroll
            for (int ni = 0; ni < 4; ++ni)
                acc[mi][ni] = __builtin_amdgcn_mfma_f32_16x16x32_bf16(a[mi], b[ni], acc[mi][ni], 0, 0, 0);
        __builtin_amdgcn_s_setprio(0);
    }

    const int cl = lane & 15;
    const int rq = (lane >> 4) * 4;
    #pragma unroll
    for (int mi = 0; mi < 4; ++mi) {
        #pragma unroll
        for (int ni = 0; ni < 4; ++ni) {
            int col = n0 + wc * 64 + ni * 16 + cl;
            #pragma unroll
            for (int rr = 0; rr < 4; ++rr) {
                int row = m0 + wr * 64 + mi * 16 + rq + rr;
                size_t idx = (size_t)row * N + col;
                float v = acc[mi][ni][rr];
                if (MODE == 2)      C[idx] = v + bias[col];
                else                C[idx] = v;
            }
        }
    }
}

// ---------------- MFMA GEMM 256x256 (head), BK=32, 512 thr, depth-4 rotation ----------------
// epilogue: per-wave LDS transpose (reuse As) -> nontemporal dwordx4 stores
__global__ __launch_bounds__(512) void gemm256(const u16* __restrict__ A,
                                               const u16* __restrict__ B,
                                               float* __restrict__ C,
                                               const float* __restrict__ bias,
                                               int M, int N, int K,
                                               int nbx, int swzq) {
    __shared__ u16 As[4][256 * 32];
    __shared__ u16 Bs[4][256 * 32];
    const int tid = threadIdx.x;
    const int wave = tid >> 6;
    const int lane = tid & 63;
    int lin = blockIdx.x;
    if (swzq) lin = (lin & 7) * swzq + (lin >> 3);
    const int m0 = (lin % nbx) * 256;
    const int n0 = (lin / nbx) * 256;
    const int wrM = wave >> 2;
    const int wcN = wave & 3;
    f32x4 acc[8][4] = {};

    const int sub = lane >> 2;
    const int slotL = lane & 3;
    const int fsub = (sub & 3) ^ ((sub >> 2) & 3);
    const int scol = (slotL ^ fsub) * 8;

    auto stage = [&](int buf, int kt) {
        int k0 = kt * 32;
        #pragma unroll
        for (int i = 0; i < 4; ++i) {
            int c = wave * 4 + i;
            const u16* src;
            u16* dst;
            if (c < 16) {
                int row = c * 16 + sub;
                src = A + (size_t)(m0 + row) * K + k0 + scol;
                dst = &As[buf][c * 512];
            } else {
                int cc = c - 16;
                int row = cc * 16 + sub;
                src = B + (size_t)(n0 + row) * K + k0 + scol;
                dst = &Bs[buf][cc * 512];
            }
            __builtin_amdgcn_global_load_lds((const __attribute__((address_space(1))) void*)src,
                                             (__attribute__((address_space(3))) void*)dst,
                                             16, 0, 0);
        }
    };

    const int nt = K / 32;
    stage(0, 0); stage(1, 1); stage(2, 2);

    const int fr = lane & 15;
    const int q = lane >> 4;
    const int fswz = (fr & 3) ^ ((fr >> 2) & 3);
    const int rdoff = ((q ^ fswz) * 8);

    for (int t = 0; t < nt; ++t) {
        if (t + 2 < nt)      asm volatile("s_waitcnt vmcnt(8)" ::: "memory");
        else if (t + 1 < nt) asm volatile("s_waitcnt vmcnt(4)" ::: "memory");
        else                 asm volatile("s_waitcnt vmcnt(0)" ::: "memory");
        __builtin_amdgcn_sched_barrier(0);
        __builtin_amdgcn_s_barrier();
        asm volatile("" ::: "memory");
        __builtin_amdgcn_sched_barrier(0);
        if (t + 3 < nt) stage((t + 3) & 3, t + 3);
        const u16* Ab = &As[t & 3][0];
        const u16* Bb = &Bs[t & 3][0];
        bf16x8 a[8], b[4];
        #pragma unroll
        for (int mi = 0; mi < 8; ++mi)
            a[mi] = *(const bf16x8*)(Ab + (wrM * 128 + mi * 16 + fr) * 32 + rdoff);
        #pragma unroll
        for (int ni = 0; ni < 4; ++ni)
            b[ni] = *(const bf16x8*)(Bb + (wcN * 64 + ni * 16 + fr) * 32 + rdoff);
        __builtin_amdgcn_s_setprio(1);
        #pragma unroll
        for (int mi = 0; mi < 8; ++mi)
            #pragma unroll
            for (int ni = 0; ni < 4; ++ni)
                acc[mi][ni] = __builtin_amdgcn_mfma_f32_16x16x32_bf16(a[mi], b[ni], acc[mi][ni], 0, 0, 0);
        __builtin_amdgcn_s_setprio(0);
    }

    // all waves done with staging buffers before reusing As as transpose scratch
    __syncthreads();
    float* slice = (float*)(&As[0][0]) + wave * (16 * 72);
    const int cl = lane & 15;                  // col within 16-col group
    const int qq = lane >> 4;                  // 0..3
    float bv[4];
    #pragma unroll
    for (int ni = 0; ni < 4; ++ni) bv[ni] = bias[n0 + wcN * 64 + ni * 16 + cl];
    #pragma unroll
    for (int mi = 0; mi < 8; ++mi) {
        #pragma unroll
        for (int ni = 0; ni < 4; ++ni)
            #pragma unroll
            for (int rr = 0; rr < 4; ++rr)
                slice[(qq * 4 + rr) * 72 + ni * 16 + cl] = acc[mi][ni][rr] + bv[ni];
        #pragma unroll
        for (int k = 0; k < 4; ++k) {
            int rl = k * 4 + qq;               // row 0..15 within the 16-row strip
            f32x4 v = *(const f32x4*)(&slice[rl * 72 + cl * 4]);
            int row = m0 + wrM * 128 + mi * 16 + rl;
            __builtin_nontemporal_store(v, (f32x4*)(C + (size_t)row * N + n0 + wcN * 64 + cl * 4));
        }
    }
}

// ---------------- MFMA GEMM 64x64, BK=64, depth-4 rotation, counted vmcnt ----------------
template <int MODE>
__global__ __launch_bounds__(256) void gemm64(const u16* __restrict__ A,
                                              const u16* __restrict__ B,
                                              float* __restrict__ C,
                                              int M, int N, int K,
                                              int nbx, int swzq) {
    __shared__ u16 As[4][64 * 64];
    __shared__ u16 Bs[4][64 * 64];
    const int tid = threadIdx.x;
    const int wave = tid >> 6;
    const int lane = tid & 63;
    int lin = blockIdx.x;
    if (swzq) lin = (lin & 7) * swzq + (lin >> 3);
    const int m0 = (lin % nbx) * 64;
    const int n0 = (lin / nbx) * 64;
    const int wr = wave >> 1, wc = wave & 1;
    f32x4 acc[2][2] = {};

    const int crow = lane >> 3;
    const int scol = ((lane & 7) ^ crow) * 8;

    auto stage = [&](int buf, int kt) {
        int k0 = kt * 64;
        #pragma unroll
        for (int i = 0; i < 4; ++i) {
            int c = wave * 4 + i;
            const u16* src;
            u16* dst;
            if (c < 8) {
                int row = c * 8 + crow;
                src = A + (size_t)(m0 + row) * K + k0 + scol;
                dst = &As[buf][c * 512];
            } else {
                int cc = c - 8;
                int row = cc * 8 + crow;
                src = B + (size_t)(n0 + row) * K + k0 + scol;
                dst = &Bs[buf][cc * 512];
            }
            __builtin_amdgcn_global_load_lds((const __attribute__((address_space(1))) void*)src,
                                             (__attribute__((address_space(3))) void*)dst,
                                             16, 0, 0);
        }
    };

    const int nt = K / 64;
    stage(0, 0); stage(1, 1); stage(2, 2);

    const int fr = lane & 15;
    const int q = lane >> 4;

    for (int t = 0; t < nt; ++t) {
        if (t + 2 < nt)      asm volatile("s_waitcnt vmcnt(8)" ::: "memory");
        else if (t + 1 < nt) asm volatile("s_waitcnt vmcnt(4)" ::: "memory");
        else                 asm volatile("s_waitcnt vmcnt(0)" ::: "memory");
        __builtin_amdgcn_sched_barrier(0);
        __builtin_amdgcn_s_barrier();
        asm volatile("" ::: "memory");
        __builtin_amdgcn_sched_barrier(0);
        if (t + 3 < nt) stage((t + 3) & 3, t + 3);
        const u16* Ab = &As[t & 3][0];
        const u16* Bb = &Bs[t & 3][0];
        bf16x8 a[2][2], b[2][2];
        #pragma unroll
        for (int ki = 0; ki < 2; ++ki) {
            #pragma unroll
            for (int mi = 0; mi < 2; ++mi) {
                int row = wr * 32 + mi * 16 + fr;
                a[ki][mi] = *(const bf16x8*)(Ab + row * 64 + ((((ki << 2) + q) ^ (fr & 7)) * 8));
            }
            #pragma unroll
            for (int ni = 0; ni < 2; ++ni) {
                int row = wc * 32 + ni * 16 + fr;
                b[ki][ni] = *(const bf16x8*)(Bb + row * 64 + ((((ki << 2) + q) ^ (fr & 7)) * 8));
            }
        }
        __builtin_amdgcn_s_setprio(1);
        #pragma unroll
        for (int ki = 0; ki < 2; ++ki)
            #pragma unroll
            for (int mi = 0; mi < 2; ++mi)
                #pragma unroll
                for (int ni = 0; ni < 2; ++ni)
                    acc[mi][ni] = __builtin_amdgcn_mfma_f32_16x16x32_bf16(a[ki][mi], b[ki][ni], acc[mi][ni], 0, 0, 0);
        __builtin_amdgcn_s_setprio(0);
    }

    const int cl = lane & 15;
    const int rq = (lane >> 4) * 4;
    #pragma unroll
    for (int mi = 0; mi < 2; ++mi) {
        #pragma unroll
        for (int ni = 0; ni < 2; ++ni) {
            int col = n0 + wc * 32 + ni * 16 + cl;
            #pragma unroll
            for (int rr = 0; rr < 4; ++rr) {
                int row = m0 + wr * 32 + mi * 16 + rq + rr;
                size_t idx = (size_t)row * N + col;
                float v = acc[mi][ni][rr];
                if (MODE == 1)      C[idx] += v;
                else                C[idx] = v;
            }
        }
    }
}

// ---------------- fused conv+silu -> xproj -> dt+softplus (8 rows/block) ----------------
__global__ __launch_bounds__(256) void conv_xproj_dt(const float* __restrict__ xz,
                                                     const float* __restrict__ cw,
                                                     const float* __restrict__ cb,
                                                     const float* __restrict__ xw,
                                                     const float* __restrict__ dtwT,
                                                     const float* __restrict__ dtb,
                                                     float* __restrict__ xc,
                                                     float* __restrict__ dbc,
                                                     float* __restrict__ delta) {
    __shared__ float sxc[8 * 1024];
    __shared__ float sxw[64 * 132];
    __shared__ float sred[4][8][68];
    __shared__ float sdbc[8][64];
    int t = threadIdx.x;
    int m0 = blockIdx.x * 8;
    #pragma unroll
    for (int i = 0; i < 32; ++i) {
        int idx = t + i * 256;
        int mi = idx >> 10, d = idx & 1023;
        int m = m0 + mi;
        int l = m & (L_ - 1);
        float acc = cb[d];
        #pragma unroll
        for (int j = 0; j < 4; ++j) {
            int ll = l - 3 + j;
            if (ll >= 0) acc = fmaf(cw[d * 4 + j], xz[(size_t)(m - 3 + j) * (2 * DINNER_) + d], acc);
        }
        float sv = acc / (1.0f + __expf(-acc));
        sxc[mi * 1024 + d] = sv;
        xc[(size_t)m * DINNER_ + d] = sv;
    }
    const int n = t & 63, kg = t >> 6;
    float acc8[8] = {};
    for (int kc = 0; kc < 8; ++kc) {
        __syncthreads();
        #pragma unroll
        for (int i = 0; i < 8; ++i) {
            int f = t + i * 256;
            int row = f >> 5, col4 = f & 31;
            *(float4*)(&sxw[row * 132 + col4 * 4]) =
                *(const float4*)(xw + (size_t)row * DINNER_ + kc * 128 + col4 * 4);
        }
        __syncthreads();
        #pragma unroll
        for (int k4i = 0; k4i < 8; ++k4i) {
            int k4 = kg * 8 + k4i;
            float4 wv = *(const float4*)(&sxw[n * 132 + k4 * 4]);
            #pragma unroll
            for (int mi = 0; mi < 8; ++mi) {
                float4 xv = *(const float4*)(&sxc[mi * 1024 + kc * 128 + k4 * 4]);
                acc8[mi] += wv.x * xv.x + wv.y * xv.y + wv.z * xv.z + wv.w * xv.w;
            }
        }
    }
    #pragma unroll
    for (int mi = 0; mi < 8; ++mi) sred[kg][mi][n] = acc8[mi];
    __syncthreads();
    #pragma unroll
    for (int rep = 0; rep < 2; ++rep) {
        int o = t + rep * 256;
        int mi = o >> 6, n2 = o & 63;
        float v = sred[0][mi][n2] + sred[1][mi][n2] + sred[2][mi][n2] + sred[3][mi][n2];
        sdbc[mi][n2] = v;
        dbc[(size_t)(m0 + mi) * 64 + n2] = v;
    }
    __syncthreads();
    {
        int d0 = t * 4;
        float4 bias = *(const float4*)(dtb + d0);
        float4 am[8];
        #pragma unroll
        for (int mi = 0; mi < 8; ++mi) am[mi] = bias;
        const float4* wT = (const float4*)dtwT;
        #pragma unroll
        for (int r = 0; r < 32; ++r) {
            float4 wv = wT[r * 256 + t];
            #pragma unroll
            for (int mi = 0; mi < 8; ++mi) {
                float s = sdbc[mi][r];
                am[mi].x = fmaf(s, wv.x, am[mi].x);
                am[mi].y = fmaf(s, wv.y, am[mi].y);
                am[mi].z = fmaf(s, wv.z, am[mi].z);
                am[mi].w = fmaf(s, wv.w, am[mi].w);
            }
        }
        #pragma unroll
        for (int mi = 0; mi < 8; ++mi) {
            float4 o;
            o.x = (am[mi].x > 20.f) ? am[mi].x : log1pf(__expf(am[mi].x));
            o.y = (am[mi].y > 20.f) ? am[mi].y : log1pf(__expf(am[mi].y));
            o.z = (am[mi].z > 20.f) ? am[mi].z : log1pf(__expf(am[mi].z));
            o.w = (am[mi].w > 20.f) ? am[mi].w : log1pf(__expf(am[mi].w));
            *(float4*)(delta + (size_t)(m0 + mi) * DINNER_ + d0) = o;
        }
    }
}

// ---------------- SSM pass 1: per-chunk local scan (h0=0) ----------------
__global__ __launch_bounds__(256) void ssm_part1(const float* __restrict__ delta,
                                                 const float* __restrict__ xc,
                                                 const float* __restrict__ dbc,
                                                 const float* __restrict__ A_log,
                                                 float* __restrict__ hfin,
                                                 float* __restrict__ sumd) {
    int tid = threadIdx.x;
    int d = blockIdx.x * 256 + tid;
    int c = blockIdx.y;
    int b = blockIdx.z;
    __shared__ float sB[CLEN][DSTATE_];
    {
        int l = tid >> 4, s = tid & 15;
        sB[l][s] = dbc[((size_t)(b * L_ + c * CLEN + l)) * 64 + DTRANK_ + s];
    }
    float A[16], h[16];
    {
        const float4* Ar = (const float4*)(A_log + (size_t)d * DSTATE_);
        #pragma unroll
        for (int i = 0; i < 4; ++i) {
            float4 al = Ar[i];
            A[i * 4 + 0] = -__expf(al.x); A[i * 4 + 1] = -__expf(al.y);
            A[i * 4 + 2] = -__expf(al.z); A[i * 4 + 3] = -__expf(al.w);
        }
    }
    #pragma unroll
    for (int s = 0; s < 16; ++s) h[s] = 0.f;
    __syncthreads();
    float sd = 0.f;
    size_t base = ((size_t)b * L_ + c * CLEN) * DINNER_ + d;
    #pragma unroll
    for (int l = 0; l < CLEN; ++l) {
        float dv = delta[base + (size_t)l * DINNER_];
        float xv = xc[base + (size_t)l * DINNER_];
        sd += dv;
        float dx = dv * xv;
        #pragma unroll
        for (int s = 0; s < 16; ++s) {
            float e = __expf(dv * A[s]);
            h[s] = fmaf(e, h[s], dx * sB[l][s]);
        }
    }
    float* hf = hfin + (((size_t)b * NCHUNK + c) * DINNER_ + d) * 16;
    #pragma unroll
    for (int i = 0; i < 4; ++i) {
        float4 v; v.x = h[i*4]; v.y = h[i*4+1]; v.z = h[i*4+2]; v.w = h[i*4+3];
        *(float4*)(hf + i * 4) = v;
    }
    sumd[((size_t)b * NCHUNK + c) * DINNER_ + d] = sd;
}

// ---------------- SSM pass 2: carry propagation across chunks ----------------
__global__ __launch_bounds__(256) void ssm_carry(const float* __restrict__ hfin,
                                                 const float* __restrict__ sumd,
                                                 const float* __restrict__ A_log,
                                                 float* __restrict__ h0buf) {
    int t = blockIdx.x * 256 + threadIdx.x;
    int s = t & 15;
    int dg = t >> 4;
    int d = dg & (DINNER_ - 1);
    int b = dg >> 10;
    float As = -__expf(A_log[(size_t)d * DSTATE_ + s]);
    float hc = 0.f;
    #pragma unroll 4
    for (int c = 0; c < NCHUNK; ++c) {
        size_t k = (((size_t)b * NCHUNK + c) * DINNER_ + d) * 16 + s;
        h0buf[k] = hc;
        float sdv = sumd[((size_t)b * NCHUNK + c) * DINNER_ + d];
        float hf = hfin[k];
        hc = fmaf(__expf(As * sdv), hc, hf);
    }
}

// ---------------- SSM pass 3: local scan w/ carry + y + gate -> ys(bf16) ----------------
__global__ __launch_bounds__(256) void ssm_part2(const float* __restrict__ delta,
                                                 const float* __restrict__ xc,
                                                 const float* __restrict__ dbc,
                                                 const float* __restrict__ xz,
                                                 const float* __restrict__ A_log,
                                                 const float* __restrict__ Dp,
                                                 const float* __restrict__ h0buf,
                                                 u16* __restrict__ ys) {
    int tid = threadIdx.x;
    int d = blockIdx.x * 256 + tid;
    int c = blockIdx.y;
    int b = blockIdx.z;
    __shared__ float sBC[CLEN][32];
    {
        int l = tid >> 5, j = tid & 31;
        sBC[l][j] = dbc[((size_t)(b * L_ + c * CLEN + l)) * 64 + DTRANK_ + j];
        int e1 = tid + 256;
        l = e1 >> 5; j = e1 & 31;
        sBC[l][j] = dbc[((size_t)(b * L_ + c * CLEN + l)) * 64 + DTRANK_ + j];
    }
    float A[16], h[16];
    {
        const float4* Ar = (const float4*)(A_log + (size_t)d * DSTATE_);
        #pragma unroll
        for (int i = 0; i < 4; ++i) {
            float4 al = Ar[i];
            A[i * 4 + 0] = -__expf(al.x); A[i * 4 + 1] = -__expf(al.y);
            A[i * 4 + 2] = -__expf(al.z); A[i * 4 + 3] = -__expf(al.w);
        }
        const float4* h0 = (const float4*)(h0buf + (((size_t)b * NCHUNK + c) * DINNER_ + d) * 16);
        #pragma unroll
        for (int i = 0; i < 4; ++i) {
            float4 v = h0[i];
            h[i * 4 + 0] = v.x; h[i * 4 + 1] = v.y; h[i * 4 + 2] = v.z; h[i * 4 + 3] = v.w;
        }
    }
    float Dval = Dp[d];
    __syncthreads();
    size_t base = ((size_t)b * L_ + c * CLEN) * DINNER_ + d;
    size_t zbase = ((size_t)b * L_ + c * CLEN) * (2 * DINNER_) + DINNER_ + d;
    #pragma unroll
    for (int l = 0; l < CLEN; ++l) {
        float dv = delta[base + (size_t)l * DINNER_];
        float xv = xc[base + (size_t)l * DINNER_];
        float zv = xz[zbase + (size_t)l * (2 * DINNER_)];
        float dx = dv * xv;
        float y = 0.f;
        #pragma unroll
        for (int s = 0; s < 16; ++s) {
            float e = __expf(dv * A[s]);
            h[s] = fmaf(e, h[s], dx * sBC[l][s]);
            y = fmaf(h[s], sBC[l][16 + s], y);
        }
        y = fmaf(Dval, xv, y);
        float sg = zv / (1.0f + __expf(-zv));
        ys[base + (size_t)l * DINNER_] = f2bf(y * sg);
    }
}

extern "C" void kernel_launch(void* const* d_in, const int* in_sizes, int n_in,
                              void* d_out, int out_size, void* d_ws, size_t ws_size,
                              hipStream_t stream) {
    const int*   x       = (const int*)d_in[0];
    const float* embed   = (const float*)d_in[1];
    const float* rms_w   = (const float*)d_in[2];
    const float* in_w    = (const float*)d_in[3];
    const float* conv_w  = (const float*)d_in[4];
    const float* conv_b  = (const float*)d_in[5];
    const float* xproj_w = (const float*)d_in[6];
    const float* dt_w    = (const float*)d_in[7];
    const float* dt_b    = (const float*)d_in[8];
    const float* A_log   = (const float*)d_in[9];
    const float* Dp      = (const float*)d_in[10];
    const float* out_w   = (const float*)d_in[11];
    const float* ln_g    = (const float*)d_in[12];
    const float* ln_b    = (const float*)d_in[13];
    const float* head_w  = (const float*)d_in[14];
    const float* head_b  = (const float*)d_in[15];
    float* out = (float*)d_out;

    char* p = (char*)d_ws;
    auto take = [&](size_t n) { char* q = p; p += (n + 255) & ~(size_t)255; return q; };
    float* h    = (float*)take(2048ull * 512 * 4);
    u16*   r_bf = (u16*)  take(2048ull * 512 * 2);
    float* xz   = (float*)take(2048ull * 2048 * 4);
    float* xc   = (float*)take(2048ull * 1024 * 4);
    float* dbc  = (float*)take(2048ull * 64 * 4);
    float* dlt  = (float*)take(2048ull * 1024 * 4);
    u16*   ys   = (u16*)  take(2048ull * 1024 * 2);
    u16*   hn   = (u16*)  take(2048ull * 512 * 2);
    u16*   win  = (u16*)  take(2ull * 2048 * 512 * 2);
    u16*   wout = (u16*)  take(2ull * 512 * 1024 * 2);
    u16*   whd  = (u16*)  take(32000ull * 512 * 2);
    float* dtwT = (float*)take(2ull * 32 * 1024 * 4);
    float* hfin = (float*)take((size_t)B_ * NCHUNK * DINNER_ * 16 * 4);
    float* h0b  = (float*)take((size_t)B_ * NCHUNK * DINNER_ * 16 * 4);
    float* sumd = (float*)take((size_t)B_ * NCHUNK * DINNER_ * 4);

    prep<<<19840, 256, 0, stream>>>(in_w, out_w, head_w, dt_w, x, embed, rms_w,
                                    win, wout, whd, dtwT, h, r_bf);

    for (int l = 0; l < 2; ++l) {
        if (l > 0) rmsnorm_bf16<<<512, 256, 0, stream>>>(h, rms_w + l * DIM_, r_bf);
        // xz = r_bf(2048x512) @ win^T(2048x512) : 128^2 tiles, grid 16x16=256, swzq=32
        gemm_bt<0><<<256, 256, 0, stream>>>(r_bf, win + (size_t)l * 2048 * 512, xz, nullptr, 2048, 2048, 512, 16, 32);
        conv_xproj_dt<<<256, 256, 0, stream>>>(xz, conv_w + l * DINNER_ * 4, conv_b + l * DINNER_,
                                               xproj_w + (size_t)l * 64 * 1024,
                                               dtwT + (size_t)l * 32 * 1024, dt_b + l * DINNER_,
                                               xc, dbc, dlt);
        ssm_part1<<<dim3(4, NCHUNK, B_), 256, 0, stream>>>(dlt, xc, dbc, A_log + (size_t)l * DINNER_ * DSTATE_, hfin, sumd);
        ssm_carry<<<128, 256, 0, stream>>>(hfin, sumd, A_log + (size_t)l * DINNER_ * DSTATE_, h0b);
        ssm_part2<<<dim3(4, NCHUNK, B_), 256, 0, stream>>>(dlt, xc, dbc, xz, A_log + (size_t)l * DINNER_ * DSTATE_,
                                                           Dp + l * DINNER_, h0b, ys);
        // h += ys(2048x1024) @ wout^T(512x1024) : grid 32x8=256, swzq=32
        gemm64<1><<<256, 256, 0, stream>>>(ys, wout + (size_t)l * 512 * 1024, h, 2048, 512, 1024, 32, 32);
    }

    layernorm_bf16<<<512, 256, 0, stream>>>(h, ln_g, ln_b, hn);
    // logits = hn(2048x512) @ whd^T(32000x512) + head_b : 256^2 tiles, grid 8x125=1000, swzq=125
    gemm256<<<1000, 512, 0, stream>>>(hn, whd, out, head_b, 2048, VOCAB_, 512, 8, 125);
}

// Round 11
// 335.695 us; speedup vs baseline: 1.1992x; 1.0179x over previous
//
#include <hip/hip_runtime.h>

typedef unsigned short u16;
typedef __attribute__((ext_vector_type(8))) __bf16 bf16x8;
typedef __attribute__((ext_vector_type(4))) float f32x4;

#define B_ 2
#define L_ 1024
#define DIM_ 512
#define DINNER_ 1024
#define DSTATE_ 16
#define DTRANK_ 32
#define VOCAB_ 32000
#define NCHUNK 64
#define CLEN 16

__device__ __forceinline__ u16 f2bf(float f) {
    union { float f; unsigned u; } x; x.f = f;
    unsigned r = x.u + 0x7FFFu + ((x.u >> 16) & 1u);
    return (u16)(r >> 16);
}

// ---------------- prep: weight bf16 conversions + dtw transpose + embed+rms ----------------
__global__ __launch_bounds__(256) void prep(const float* __restrict__ in_w,
                                            const float* __restrict__ out_w,
                                            const float* __restrict__ head_w,
                                            const float* __restrict__ dt_w,
                                            const int* __restrict__ x,
                                            const float* __restrict__ embed,
                                            const float* __restrict__ rw,
                                            u16* __restrict__ win,
                                            u16* __restrict__ wout,
                                            u16* __restrict__ whd,
                                            float* __restrict__ dtwT,
                                            float* __restrict__ h,
                                            u16* __restrict__ rbf) {
    int bk = blockIdx.x;
    int t = threadIdx.x;
    if (bk < 19072) {
        const int n1 = 524288;
        const int n2 = n1 + 262144;
        int i = bk * 256 + t;
        const float4* s; ushort4* d; int j;
        if (i < n1)      { s = (const float4*)in_w;   d = (ushort4*)win;  j = i; }
        else if (i < n2) { s = (const float4*)out_w;  d = (ushort4*)wout; j = i - n1; }
        else             { s = (const float4*)head_w; d = (ushort4*)whd;  j = i - n2; }
        float4 v = s[j];
        ushort4 o; o.x = f2bf(v.x); o.y = f2bf(v.y); o.z = f2bf(v.z); o.w = f2bf(v.w);
        d[j] = o;
    } else if (bk < 19328) {
        int bb = bk - 19072;
        int l = bb >> 7;
        int e = (bb & 127) * 256 + t;
        int r = e >> 10, d = e & 1023;
        dtwT[(size_t)l * 32768 + r * 1024 + d] = dt_w[(size_t)l * 32768 + d * 32 + r];
    } else {
        int wave = t >> 6, lane = t & 63;
        int row = (bk - 19328) * 4 + wave;
        int tok = x[row];
        const float4* s = (const float4*)(embed + (size_t)tok * DIM_);
        float4 v0 = s[lane], v1 = s[lane + 64];
        float4* hd = (float4*)(h + (size_t)row * DIM_);
        hd[lane] = v0;
        hd[lane + 64] = v1;
        float ss = v0.x*v0.x + v0.y*v0.y + v0.z*v0.z + v0.w*v0.w
                 + v1.x*v1.x + v1.y*v1.y + v1.z*v1.z + v1.w*v1.w;
        for (int m = 1; m < 64; m <<= 1) ss += __shfl_xor(ss, m);
        float rms = rsqrtf(ss * (1.0f / DIM_) + 1e-5f);
        const float4* w4 = (const float4*)rw;
        float4 w0 = w4[lane], w1 = w4[lane + 64];
        u16* o = rbf + (size_t)row * DIM_;
        ushort4 a, b;
        a.x = f2bf(v0.x * rms * w0.x); a.y = f2bf(v0.y * rms * w0.y);
        a.z = f2bf(v0.z * rms * w0.z); a.w = f2bf(v0.w * rms * w0.w);
        b.x = f2bf(v1.x * rms * w1.x); b.y = f2bf(v1.y * rms * w1.y);
        b.z = f2bf(v1.z * rms * w1.z); b.w = f2bf(v1.w * rms * w1.w);
        *(ushort4*)(o + lane * 4) = a;
        *(ushort4*)(o + 256 + lane * 4) = b;
    }
}

// ---------------- RMSNorm -> bf16 ----------------
__global__ __launch_bounds__(256) void rmsnorm_bf16(const float* __restrict__ h,
                                                    const float* __restrict__ w,
                                                    u16* __restrict__ out) {
    int wave = threadIdx.x >> 6, lane = threadIdx.x & 63;
    int row = blockIdx.x * 4 + wave;
    const float4* r4 = (const float4*)(h + (size_t)row * DIM_);
    float4 v0 = r4[lane], v1 = r4[lane + 64];
    float ss = v0.x*v0.x + v0.y*v0.y + v0.z*v0.z + v0.w*v0.w
             + v1.x*v1.x + v1.y*v1.y + v1.z*v1.z + v1.w*v1.w;
    for (int m = 1; m < 64; m <<= 1) ss += __shfl_xor(ss, m);
    float rms = rsqrtf(ss * (1.0f / DIM_) + 1e-5f);
    const float4* w4 = (const float4*)w;
    float4 w0 = w4[lane], w1 = w4[lane + 64];
    u16* o = out + (size_t)row * DIM_;
    ushort4 a, b;
    a.x = f2bf(v0.x * rms * w0.x); a.y = f2bf(v0.y * rms * w0.y);
    a.z = f2bf(v0.z * rms * w0.z); a.w = f2bf(v0.w * rms * w0.w);
    b.x = f2bf(v1.x * rms * w1.x); b.y = f2bf(v1.y * rms * w1.y);
    b.z = f2bf(v1.z * rms * w1.z); b.w = f2bf(v1.w * rms * w1.w);
    *(ushort4*)(o + lane * 4) = a;
    *(ushort4*)(o + 256 + lane * 4) = b;
}

// ---------------- LayerNorm -> bf16 ----------------
__global__ __launch_bounds__(256) void layernorm_bf16(const float* __restrict__ h,
                                                      const float* __restrict__ g,
                                                      const float* __restrict__ bta,
                                                      u16* __restrict__ out) {
    int wave = threadIdx.x >> 6, lane = threadIdx.x & 63;
    int row = blockIdx.x * 4 + wave;
    const float4* r4 = (const float4*)(h + (size_t)row * DIM_);
    float4 v0 = r4[lane], v1 = r4[lane + 64];
    float s = v0.x + v0.y + v0.z + v0.w + v1.x + v1.y + v1.z + v1.w;
    float ss = v0.x*v0.x + v0.y*v0.y + v0.z*v0.z + v0.w*v0.w
             + v1.x*v1.x + v1.y*v1.y + v1.z*v1.z + v1.w*v1.w;
    for (int m = 1; m < 64; m <<= 1) { s += __shfl_xor(s, m); ss += __shfl_xor(ss, m); }
    float mu = s * (1.0f / DIM_);
    float var = ss * (1.0f / DIM_) - mu * mu;
    float rs = rsqrtf(var + 1e-5f);
    const float4* g4 = (const float4*)g;
    const float4* b4 = (const float4*)bta;
    float4 g0 = g4[lane], g1 = g4[lane + 64];
    float4 b0 = b4[lane], b1 = b4[lane + 64];
    u16* o = out + (size_t)row * DIM_;
    ushort4 a, b;
    a.x = f2bf((v0.x - mu) * rs * g0.x + b0.x); a.y = f2bf((v0.y - mu) * rs * g0.y + b0.y);
    a.z = f2bf((v0.z - mu) * rs * g0.z + b0.z); a.w = f2bf((v0.w - mu) * rs * g0.w + b0.w);
    b.x = f2bf((v1.x - mu) * rs * g1.x + b1.x); b.y = f2bf((v1.y - mu) * rs * g1.y + b1.y);
    b.z = f2bf((v1.z - mu) * rs * g1.z + b1.z); b.w = f2bf((v1.w - mu) * rs * g1.w + b1.w);
    *(ushort4*)(o + lane * 4) = a;
    *(ushort4*)(o + 256 + lane * 4) = b;
}

// ---------------- MFMA GEMM 128x128, BK=32, depth-4 rotation, counted vmcnt ----------------
template <int MODE>
__global__ __launch_bounds__(256) void gemm_bt(const u16* __restrict__ A,
                                               const u16* __restrict__ B,
                                               float* __restrict__ C,
                                               const float* __restrict__ bias,
                                               int M, int N, int K,
                                               int nbx, int swzq) {
    __shared__ u16 As[4][128 * 32];
    __shared__ u16 Bs[4][128 * 32];
    const int tid = threadIdx.x;
    const int wave = tid >> 6;
    const int lane = tid & 63;
    int lin = blockIdx.x;
    if (swzq) lin = (lin & 7) * swzq + (lin >> 3);
    const int m0 = (lin % nbx) * 128;
    const int n0 = (lin / nbx) * 128;
    const int wr = wave >> 1, wc = wave & 1;
    f32x4 acc[4][4] = {};

    const int sub = lane >> 2;
    const int slotL = lane & 3;
    const int fsub = (sub & 3) ^ ((sub >> 2) & 3);
    const int scol = (slotL ^ fsub) * 8;

    auto stage = [&](int buf, int kt) {
        int k0 = kt * 32;
        #pragma unroll
        for (int i = 0; i < 4; ++i) {
            int c = wave * 4 + i;
            const u16* src;
            u16* dst;
            if (c < 8) {
                int row = c * 16 + sub;
                src = A + (size_t)(m0 + row) * K + k0 + scol;
                dst = &As[buf][c * 512];
            } else {
                int cc = c - 8;
                int row = cc * 16 + sub;
                src = B + (size_t)(n0 + row) * K + k0 + scol;
                dst = &Bs[buf][cc * 512];
            }
            __builtin_amdgcn_global_load_lds((const __attribute__((address_space(1))) void*)src,
                                             (__attribute__((address_space(3))) void*)dst,
                                             16, 0, 0);
        }
    };

    const int nt = K / 32;
    stage(0, 0); stage(1, 1); stage(2, 2);

    const int fr = lane & 15;
    const int q = lane >> 4;
    const int fswz = (fr & 3) ^ ((fr >> 2) & 3);
    const int rdoff = ((q ^ fswz) * 8);

    for (int t = 0; t < nt; ++t) {
        if (t + 2 < nt)      asm volatile("s_waitcnt vmcnt(8)" ::: "memory");
        else if (t + 1 < nt) asm volatile("s_waitcnt vmcnt(4)" ::: "memory");
        else                 asm volatile("s_waitcnt vmcnt(0)" ::: "memory");
        __builtin_amdgcn_sched_barrier(0);
        __builtin_amdgcn_s_barrier();
        asm volatile("" ::: "memory");
        __builtin_amdgcn_sched_barrier(0);
        if (t + 3 < nt) stage((t + 3) & 3, t + 3);
        const u16* Ab = &As[t & 3][0];
        const u16* Bb = &Bs[t & 3][0];
        bf16x8 a[4], b[4];
        #pragma unroll
        for (int mi = 0; mi < 4; ++mi)
            a[mi] = *(const bf16x8*)(Ab + (wr * 64 + mi * 16 + fr) * 32 + rdoff);
        #pragma unroll
        for (int ni = 0; ni < 4; ++ni)
            b[ni] = *(const bf16x8*)(Bb + (wc * 64 + ni * 16 + fr) * 32 + rdoff);
        __builtin_amdgcn_s_setprio(1);
        #pragma unroll
        for (int mi = 0; mi < 4; ++mi)
            #pragma unroll
            for (int ni = 0; ni < 4; ++ni)
                acc[mi][ni] = __builtin_amdgcn_mfma_f32_16x16x32_bf16(a[mi], b[ni], acc[mi][ni], 0, 0, 0);
        __builtin_amdgcn_s_setprio(0);
    }

    const int cl = lane & 15;
    const int rq = (lane >> 4) * 4;
    #pragma unroll
    for (int mi = 0; mi < 4; ++mi) {
        #pragma unroll
        for (int ni = 0; ni < 4; ++ni) {
            int col = n0 + wc * 64 + ni * 16 + cl;
            #pragma unroll
            for (int rr = 0; rr < 4; ++rr) {
                int row = m0 + wr * 64 + mi * 16 + rq + rr;
                size_t idx = (size_t)row * N + col;
                float v = acc[mi][ni][rr];
                if (MODE == 2)      C[idx] = v + bias[col];
                else                C[idx] = v;
            }
        }
    }
}

// ---------------- MFMA GEMM head: 256(M)x128(N), BK=32, 2-phase, 2 blocks/CU ----------------
// 512 thr = 8 waves (4M x 2N), 48 KB LDS pool, VGPR capped for 4 waves/SIMD.
__global__ __launch_bounds__(512, 4) void gemm_head(const u16* __restrict__ A,
                                                    const u16* __restrict__ B,
                                                    float* __restrict__ C,
                                                    const float* __restrict__ bias,
                                                    int M, int N, int K,
                                                    int nbx, int swzq) {
    __shared__ u16 pool[2 * 8192 + 2 * 4096];      // A: 2x16KB, B: 2x8KB = 48 KB
    const int tid = threadIdx.x;
    const int wave = tid >> 6;
    const int lane = tid & 63;
    int lin = blockIdx.x;
    if (swzq) lin = (lin & 7) * swzq + (lin >> 3);
    const int m0 = (lin % nbx) * 256;
    const int n0 = (lin / nbx) * 128;
    const int wrM = wave >> 1;        // 0..3 -> 64-row strip
    const int wcN = wave & 1;         // 0..1 -> 64-col strip
    f32x4 acc[4][4] = {};

    const int sub = lane >> 2;
    const int slotL = lane & 3;
    const int fsub = (sub & 3) ^ ((sub >> 2) & 3);
    const int scol = (slotL ^ fsub) * 8;

    auto stage = [&](int buf, int kt) {
        int k0 = kt * 32;
        #pragma unroll
        for (int i = 0; i < 3; ++i) {
            int c = wave * 3 + i;                   // 0..23
            const u16* src;
            u16* dst;
            if (c < 16) {
                int row = c * 16 + sub;
                src = A + (size_t)(m0 + row) * K + k0 + scol;
                dst = pool + buf * 8192 + c * 512;
            } else {
                int cc = c - 16;
                int row = cc * 16 + sub;
                src = B + (size_t)(n0 + row) * K + k0 + scol;
                dst = pool + 16384 + buf * 4096 + cc * 512;
            }
            __builtin_amdgcn_global_load_lds((const __attribute__((address_space(1))) void*)src,
                                             (__attribute__((address_space(3))) void*)dst,
                                             16, 0, 0);
        }
    };

    const int nt = K / 32;            // 16
    stage(0, 0);
    __syncthreads();
    int cur = 0;
    const int fr = lane & 15;
    const int q = lane >> 4;
    const int fswz = (fr & 3) ^ ((fr >> 2) & 3);
    const int rdoff = ((q ^ fswz) * 8);

    for (int t = 0; t < nt; ++t) {
        if (t + 1 < nt) stage(cur ^ 1, t + 1);     // issue next tile; hides under MFMA below
        const u16* Ab = pool + cur * 8192;
        const u16* Bb = pool + 16384 + cur * 4096;
        bf16x8 a[4], b[4];
        #pragma unroll
        for (int mi = 0; mi < 4; ++mi)
            a[mi] = *(const bf16x8*)(Ab + (wrM * 64 + mi * 16 + fr) * 32 + rdoff);
        #pragma unroll
        for (int ni = 0; ni < 4; ++ni)
            b[ni] = *(const bf16x8*)(Bb + (wcN * 64 + ni * 16 + fr) * 32 + rdoff);
        __builtin_amdgcn_s_setprio(1);
        #pragma unroll
        for (int mi = 0; mi < 4; ++mi)
            #pragma unroll
            for (int ni = 0; ni < 4; ++ni)
                acc[mi][ni] = __builtin_amdgcn_mfma_f32_16x16x32_bf16(a[mi], b[ni], acc[mi][ni], 0, 0, 0);
        __builtin_amdgcn_s_setprio(0);
        __syncthreads();                           // drains next-tile loads + protects cur buffer
        cur ^= 1;
    }

    // epilogue: per-wave LDS transpose (slices carved from pool) -> nontemporal dwordx4 stores
    float* slice = (float*)pool + wave * (16 * 72);     // 8 waves x 4.6 KB = 36.8 KB <= 48 KB
    const int cl = lane & 15;
    const int qq = lane >> 4;
    float bv[4];
    #pragma unroll
    for (int ni = 0; ni < 4; ++ni) bv[ni] = bias[n0 + wcN * 64 + ni * 16 + cl];
    #pragma unroll
    for (int mi = 0; mi < 4; ++mi) {
        #pragma unroll
        for (int ni = 0; ni < 4; ++ni)
            #pragma unroll
            for (int rr = 0; rr < 4; ++rr)
                slice[(qq * 4 + rr) * 72 + ni * 16 + cl] = acc[mi][ni][rr] + bv[ni];
        #pragma unroll
        for (int k = 0; k < 4; ++k) {
            int rl = k * 4 + qq;
            f32x4 v = *(const f32x4*)(&slice[rl * 72 + cl * 4]);
            int row = m0 + wrM * 64 + mi * 16 + rl;
            __builtin_nontemporal_store(v, (f32x4*)(C + (size_t)row * N + n0 + wcN * 64 + cl * 4));
        }
    }
}

// ---------------- MFMA GEMM 64x64, BK=64, depth-4 rotation, counted vmcnt ----------------
template <int MODE>
__global__ __launch_bounds__(256) void gemm64(const u16* __restrict__ A,
                                              const u16* __restrict__ B,
                                              float* __restrict__ C,
                                              int M, int N, int K,
                                              int nbx, int swzq) {
    __shared__ u16 As[4][64 * 64];
    __shared__ u16 Bs[4][64 * 64];
    const int tid = threadIdx.x;
    const int wave = tid >> 6;
    const int lane = tid & 63;
    int lin = blockIdx.x;
    if (swzq) lin = (lin & 7) * swzq + (lin >> 3);
    const int m0 = (lin % nbx) * 64;
    const int n0 = (lin / nbx) * 64;
    const int wr = wave >> 1, wc = wave & 1;
    f32x4 acc[2][2] = {};

    const int crow = lane >> 3;
    const int scol = ((lane & 7) ^ crow) * 8;

    auto stage = [&](int buf, int kt) {
        int k0 = kt * 64;
        #pragma unroll
        for (int i = 0; i < 4; ++i) {
            int c = wave * 4 + i;
            const u16* src;
            u16* dst;
            if (c < 8) {
                int row = c * 8 + crow;
                src = A + (size_t)(m0 + row) * K + k0 + scol;
                dst = &As[buf][c * 512];
            } else {
                int cc = c - 8;
                int row = cc * 8 + crow;
                src = B + (size_t)(n0 + row) * K + k0 + scol;
                dst = &Bs[buf][cc * 512];
            }
            __builtin_amdgcn_global_load_lds((const __attribute__((address_space(1))) void*)src,
                                             (__attribute__((address_space(3))) void*)dst,
                                             16, 0, 0);
        }
    };

    const int nt = K / 64;
    stage(0, 0); stage(1, 1); stage(2, 2);

    const int fr = lane & 15;
    const int q = lane >> 4;

    for (int t = 0; t < nt; ++t) {
        if (t + 2 < nt)      asm volatile("s_waitcnt vmcnt(8)" ::: "memory");
        else if (t + 1 < nt) asm volatile("s_waitcnt vmcnt(4)" ::: "memory");
        else                 asm volatile("s_waitcnt vmcnt(0)" ::: "memory");
        __builtin_amdgcn_sched_barrier(0);
        __builtin_amdgcn_s_barrier();
        asm volatile("" ::: "memory");
        __builtin_amdgcn_sched_barrier(0);
        if (t + 3 < nt) stage((t + 3) & 3, t + 3);
        const u16* Ab = &As[t & 3][0];
        const u16* Bb = &Bs[t & 3][0];
        bf16x8 a[2][2], b[2][2];
        #pragma unroll
        for (int ki = 0; ki < 2; ++ki) {
            #pragma unroll
            for (int mi = 0; mi < 2; ++mi) {
                int row = wr * 32 + mi * 16 + fr;
                a[ki][mi] = *(const bf16x8*)(Ab + row * 64 + ((((ki << 2) + q) ^ (fr & 7)) * 8));
            }
            #pragma unroll
            for (int ni = 0; ni < 2; ++ni) {
                int row = wc * 32 + ni * 16 + fr;
                b[ki][ni] = *(const bf16x8*)(Bb + row * 64 + ((((ki << 2) + q) ^ (fr & 7)) * 8));
            }
        }
        __builtin_amdgcn_s_setprio(1);
        #pragma unroll
        for (int ki = 0; ki < 2; ++ki)
            #pragma unroll
            for (int mi = 0; mi < 2; ++mi)
                #pragma unroll
                for (int ni = 0; ni < 2; ++ni)
                    acc[mi][ni] = __builtin_amdgcn_mfma_f32_16x16x32_bf16(a[ki][mi], b[ki][ni], acc[mi][ni], 0, 0, 0);
        __builtin_amdgcn_s_setprio(0);
    }

    const int cl = lane & 15;
    const int rq = (lane >> 4) * 4;
    #pragma unroll
    for (int mi = 0; mi < 2; ++mi) {
        #pragma unroll
        for (int ni = 0; ni < 2; ++ni) {
            int col = n0 + wc * 32 + ni * 16 + cl;
            #pragma unroll
            for (int rr = 0; rr < 4; ++rr) {
                int row = m0 + wr * 32 + mi * 16 + rq + rr;
                size_t idx = (size_t)row * N + col;
                float v = acc[mi][ni][rr];
                if (MODE == 1)      C[idx] += v;
                else                C[idx] = v;
            }
        }
    }
}

// ---------------- fused conv+silu -> xproj -> dt+softplus (8 rows/block) ----------------
__global__ __launch_bounds__(256) void conv_xproj_dt(const float* __restrict__ xz,
                                                     const float* __restrict__ cw,
                                                     const float* __restrict__ cb,
                                                     const float* __restrict__ xw,
                                                     const float* __restrict__ dtwT,
                                                     const float* __restrict__ dtb,
                                                     float* __restrict__ xc,
                                                     float* __restrict__ dbc,
                                                     float* __restrict__ delta) {
    __shared__ float sxc[8 * 1024];
    __shared__ float sxw[64 * 132];
    __shared__ float sred[4][8][68];
    __shared__ float sdbc[8][64];
    int t = threadIdx.x;
    int m0 = blockIdx.x * 8;
    #pragma unroll
    for (int i = 0; i < 32; ++i) {
        int idx = t + i * 256;
        int mi = idx >> 10, d = idx & 1023;
        int m = m0 + mi;
        int l = m & (L_ - 1);
        float acc = cb[d];
        #pragma unroll
        for (int j = 0; j < 4; ++j) {
            int ll = l - 3 + j;
            if (ll >= 0) acc = fmaf(cw[d * 4 + j], xz[(size_t)(m - 3 + j) * (2 * DINNER_) + d], acc);
        }
        float sv = acc / (1.0f + __expf(-acc));
        sxc[mi * 1024 + d] = sv;
        xc[(size_t)m * DINNER_ + d] = sv;
    }
    const int n = t & 63, kg = t >> 6;
    float acc8[8] = {};
    for (int kc = 0; kc < 8; ++kc) {
        __syncthreads();
        #pragma unroll
        for (int i = 0; i < 8; ++i) {
            int f = t + i * 256;
            int row = f >> 5, col4 = f & 31;
            *(float4*)(&sxw[row * 132 + col4 * 4]) =
                *(const float4*)(xw + (size_t)row * DINNER_ + kc * 128 + col4 * 4);
        }
        __syncthreads();
        #pragma unroll
        for (int k4i = 0; k4i < 8; ++k4i) {
            int k4 = kg * 8 + k4i;
            float4 wv = *(const float4*)(&sxw[n * 132 + k4 * 4]);
            #pragma unroll
            for (int mi = 0; mi < 8; ++mi) {
                float4 xv = *(const float4*)(&sxc[mi * 1024 + kc * 128 + k4 * 4]);
                acc8[mi] += wv.x * xv.x + wv.y * xv.y + wv.z * xv.z + wv.w * xv.w;
            }
        }
    }
    #pragma unroll
    for (int mi = 0; mi < 8; ++mi) sred[kg][mi][n] = acc8[mi];
    __syncthreads();
    #pragma unroll
    for (int rep = 0; rep < 2; ++rep) {
        int o = t + rep * 256;
        int mi = o >> 6, n2 = o & 63;
        float v = sred[0][mi][n2] + sred[1][mi][n2] + sred[2][mi][n2] + sred[3][mi][n2];
        sdbc[mi][n2] = v;
        dbc[(size_t)(m0 + mi) * 64 + n2] = v;
    }
    __syncthreads();
    {
        int d0 = t * 4;
        float4 bias = *(const float4*)(dtb + d0);
        float4 am[8];
        #pragma unroll
        for (int mi = 0; mi < 8; ++mi) am[mi] = bias;
        const float4* wT = (const float4*)dtwT;
        #pragma unroll
        for (int r = 0; r < 32; ++r) {
            float4 wv = wT[r * 256 + t];
            #pragma unroll
            for (int mi = 0; mi < 8; ++mi) {
                float s = sdbc[mi][r];
                am[mi].x = fmaf(s, wv.x, am[mi].x);
                am[mi].y = fmaf(s, wv.y, am[mi].y);
                am[mi].z = fmaf(s, wv.z, am[mi].z);
                am[mi].w = fmaf(s, wv.w, am[mi].w);
            }
        }
        #pragma unroll
        for (int mi = 0; mi < 8; ++mi) {
            float4 o;
            o.x = (am[mi].x > 20.f) ? am[mi].x : log1pf(__expf(am[mi].x));
            o.y = (am[mi].y > 20.f) ? am[mi].y : log1pf(__expf(am[mi].y));
            o.z = (am[mi].z > 20.f) ? am[mi].z : log1pf(__expf(am[mi].z));
            o.w = (am[mi].w > 20.f) ? am[mi].w : log1pf(__expf(am[mi].w));
            *(float4*)(delta + (size_t)(m0 + mi) * DINNER_ + d0) = o;
        }
    }
}

// ---------------- SSM pass 1: per-chunk local scan (h0=0) ----------------
__global__ __launch_bounds__(256) void ssm_part1(const float* __restrict__ delta,
                                                 const float* __restrict__ xc,
                                                 const float* __restrict__ dbc,
                                                 const float* __restrict__ A_log,
                                                 float* __restrict__ hfin,
                                                 float* __restrict__ sumd) {
    int tid = threadIdx.x;
    int d = blockIdx.x * 256 + tid;
    int c = blockIdx.y;
    int b = blockIdx.z;
    __shared__ float sB[CLEN][DSTATE_];
    {
        int l = tid >> 4, s = tid & 15;
        sB[l][s] = dbc[((size_t)(b * L_ + c * CLEN + l)) * 64 + DTRANK_ + s];
    }
    float A[16], h[16];
    {
        const float4* Ar = (const float4*)(A_log + (size_t)d * DSTATE_);
        #pragma unroll
        for (int i = 0; i < 4; ++i) {
            float4 al = Ar[i];
            A[i * 4 + 0] = -__expf(al.x); A[i * 4 + 1] = -__expf(al.y);
            A[i * 4 + 2] = -__expf(al.z); A[i * 4 + 3] = -__expf(al.w);
        }
    }
    #pragma unroll
    for (int s = 0; s < 16; ++s) h[s] = 0.f;
    __syncthreads();
    float sd = 0.f;
    size_t base = ((size_t)b * L_ + c * CLEN) * DINNER_ + d;
    #pragma unroll
    for (int l = 0; l < CLEN; ++l) {
        float dv = delta[base + (size_t)l * DINNER_];
        float xv = xc[base + (size_t)l * DINNER_];
        sd += dv;
        float dx = dv * xv;
        #pragma unroll
        for (int s = 0; s < 16; ++s) {
            float e = __expf(dv * A[s]);
            h[s] = fmaf(e, h[s], dx * sB[l][s]);
        }
    }
    float* hf = hfin + (((size_t)b * NCHUNK + c) * DINNER_ + d) * 16;
    #pragma unroll
    for (int i = 0; i < 4; ++i) {
        float4 v; v.x = h[i*4]; v.y = h[i*4+1]; v.z = h[i*4+2]; v.w = h[i*4+3];
        *(float4*)(hf + i * 4) = v;
    }
    sumd[((size_t)b * NCHUNK + c) * DINNER_ + d] = sd;
}

// ---------------- SSM pass 2: carry propagation across chunks ----------------
__global__ __launch_bounds__(128) void ssm_carry(const float* __restrict__ hfin,
                                                 const float* __restrict__ sumd,
                                                 const float* __restrict__ A_log,
                                                 float* __restrict__ h0buf) {
    int t = blockIdx.x * 128 + threadIdx.x;
    int s = t & 15;
    int dg = t >> 4;
    int d = dg & (DINNER_ - 1);
    int b = dg >> 10;
    float As = -__expf(A_log[(size_t)d * DSTATE_ + s]);
    float hc = 0.f;
    #pragma unroll 4
    for (int c = 0; c < NCHUNK; ++c) {
        size_t k = (((size_t)b * NCHUNK + c) * DINNER_ + d) * 16 + s;
        h0buf[k] = hc;
        float sdv = sumd[((size_t)b * NCHUNK + c) * DINNER_ + d];
        float hf = hfin[k];
        hc = fmaf(__expf(As * sdv), hc, hf);
    }
}

// ---------------- SSM pass 3: local scan w/ carry + y + gate -> ys(bf16) ----------------
__global__ __launch_bounds__(256) void ssm_part2(const float* __restrict__ delta,
                                                 const float* __restrict__ xc,
                                                 const float* __restrict__ dbc,
                                                 const float* __restrict__ xz,
                                                 const float* __restrict__ A_log,
                                                 const float* __restrict__ Dp,
                                                 const float* __restrict__ h0buf,
                                                 u16* __restrict__ ys) {
    int tid = threadIdx.x;
    int d = blockIdx.x * 256 + tid;
    int c = blockIdx.y;
    int b = blockIdx.z;
    __shared__ float sBC[CLEN][32];
    {
        int l = tid >> 5, j = tid & 31;
        sBC[l][j] = dbc[((size_t)(b * L_ + c * CLEN + l)) * 64 + DTRANK_ + j];
        int e1 = tid + 256;
        l = e1 >> 5; j = e1 & 31;
        sBC[l][j] = dbc[((size_t)(b * L_ + c * CLEN + l)) * 64 + DTRANK_ + j];
    }
    float A[16], h[16];
    {
        const float4* Ar = (const float4*)(A_log + (size_t)d * DSTATE_);
        #pragma unroll
        for (int i = 0; i < 4; ++i) {
            float4 al = Ar[i];
            A[i * 4 + 0] = -__expf(al.x); A[i * 4 + 1] = -__expf(al.y);
            A[i * 4 + 2] = -__expf(al.z); A[i * 4 + 3] = -__expf(al.w);
        }
        const float4* h0 = (const float4*)(h0buf + (((size_t)b * NCHUNK + c) * DINNER_ + d) * 16);
        #pragma unroll
        for (int i = 0; i < 4; ++i) {
            float4 v = h0[i];
            h[i * 4 + 0] = v.x; h[i * 4 + 1] = v.y; h[i * 4 + 2] = v.z; h[i * 4 + 3] = v.w;
        }
    }
    float Dval = Dp[d];
    __syncthreads();
    size_t base = ((size_t)b * L_ + c * CLEN) * DINNER_ + d;
    size_t zbase = ((size_t)b * L_ + c * CLEN) * (2 * DINNER_) + DINNER_ + d;
    #pragma unroll
    for (int l = 0; l < CLEN; ++l) {
        float dv = delta[base + (size_t)l * DINNER_];
        float xv = xc[base + (size_t)l * DINNER_];
        float zv = xz[zbase + (size_t)l * (2 * DINNER_)];
        float dx = dv * xv;
        float y = 0.f;
        #pragma unroll
        for (int s = 0; s < 16; ++s) {
            float e = __expf(dv * A[s]);
            h[s] = fmaf(e, h[s], dx * sBC[l][s]);
            y = fmaf(h[s], sBC[l][16 + s], y);
        }
        y = fmaf(Dval, xv, y);
        float sg = zv / (1.0f + __expf(-zv));
        ys[base + (size_t)l * DINNER_] = f2bf(y * sg);
    }
}

extern "C" void kernel_launch(void* const* d_in, const int* in_sizes, int n_in,
                              void* d_out, int out_size, void* d_ws, size_t ws_size,
                              hipStream_t stream) {
    const int*   x       = (const int*)d_in[0];
    const float* embed   = (const float*)d_in[1];
    const float* rms_w   = (const float*)d_in[2];
    const float* in_w    = (const float*)d_in[3];
    const float* conv_w  = (const float*)d_in[4];
    const float* conv_b  = (const float*)d_in[5];
    const float* xproj_w = (const float*)d_in[6];
    const float* dt_w    = (const float*)d_in[7];
    const float* dt_b    = (const float*)d_in[8];
    const float* A_log   = (const float*)d_in[9];
    const float* Dp      = (const float*)d_in[10];
    const float* out_w   = (const float*)d_in[11];
    const float* ln_g    = (const float*)d_in[12];
    const float* ln_b    = (const float*)d_in[13];
    const float* head_w  = (const float*)d_in[14];
    const float* head_b  = (const float*)d_in[15];
    float* out = (float*)d_out;

    char* p = (char*)d_ws;
    auto take = [&](size_t n) { char* q = p; p += (n + 255) & ~(size_t)255; return q; };
    float* h    = (float*)take(2048ull * 512 * 4);
    u16*   r_bf = (u16*)  take(2048ull * 512 * 2);
    float* xz   = (float*)take(2048ull * 2048 * 4);
    float* xc   = (float*)take(2048ull * 1024 * 4);
    float* dbc  = (float*)take(2048ull * 64 * 4);
    float* dlt  = (float*)take(2048ull * 1024 * 4);
    u16*   ys   = (u16*)  take(2048ull * 1024 * 2);
    u16*   hn   = (u16*)  take(2048ull * 512 * 2);
    u16*   win  = (u16*)  take(2ull * 2048 * 512 * 2);
    u16*   wout = (u16*)  take(2ull * 512 * 1024 * 2);
    u16*   whd  = (u16*)  take(32000ull * 512 * 2);
    float* dtwT = (float*)take(2ull * 32 * 1024 * 4);
    float* hfin = (float*)take((size_t)B_ * NCHUNK * DINNER_ * 16 * 4);
    float* h0b  = (float*)take((size_t)B_ * NCHUNK * DINNER_ * 16 * 4);
    float* sumd = (float*)take((size_t)B_ * NCHUNK * DINNER_ * 4);

    prep<<<19840, 256, 0, stream>>>(in_w, out_w, head_w, dt_w, x, embed, rms_w,
                                    win, wout, whd, dtwT, h, r_bf);

    for (int l = 0; l < 2; ++l) {
        if (l > 0) rmsnorm_bf16<<<512, 256, 0, stream>>>(h, rms_w + l * DIM_, r_bf);
        // xz = r_bf(2048x512) @ win^T(2048x512) : 128^2 tiles, grid 16x16=256, swzq=32
        gemm_bt<0><<<256, 256, 0, stream>>>(r_bf, win + (size_t)l * 2048 * 512, xz, nullptr, 2048, 2048, 512, 16, 32);
        conv_xproj_dt<<<256, 256, 0, stream>>>(xz, conv_w + l * DINNER_ * 4, conv_b + l * DINNER_,
                                               xproj_w + (size_t)l * 64 * 1024,
                                               dtwT + (size_t)l * 32 * 1024, dt_b + l * DINNER_,
                                               xc, dbc, dlt);
        ssm_part1<<<dim3(4, NCHUNK, B_), 256, 0, stream>>>(dlt, xc, dbc, A_log + (size_t)l * DINNER_ * DSTATE_, hfin, sumd);
        ssm_carry<<<256, 128, 0, stream>>>(hfin, sumd, A_log + (size_t)l * DINNER_ * DSTATE_, h0b);
        ssm_part2<<<dim3(4, NCHUNK, B_), 256, 0, stream>>>(dlt, xc, dbc, xz, A_log + (size_t)l * DINNER_ * DSTATE_,
                                                           Dp + l * DINNER_, h0b, ys);
        // h += ys(2048x1024) @ wout^T(512x1024) : grid 32x8=256, swzq=32
        gemm64<1><<<256, 256, 0, stream>>>(ys, wout + (size_t)l * 512 * 1024, h, 2048, 512, 1024, 32, 32);
    }

    layernorm_bf16<<<512, 256, 0, stream>>>(h, ln_g, ln_b, hn);
    // logits = hn(2048x512) @ whd^T(32000x512) + head_b : 256x128 tiles, grid 8x250=2000, swzq=250
    gemm_head<<<2000, 512, 0, stream>>>(hn, whd, out, head_b, 2048, VOCAB_, 512, 8, 250);
}